// Round 8
// baseline (424.170 us; speedup 1.0000x reference)
//
#include <hip/hip_runtime.h>
#include <cstdint>
#include <math.h>

typedef unsigned short u16;
typedef __bf16 bf16x8 __attribute__((ext_vector_type(8)));
typedef float f32x4 __attribute__((ext_vector_type(4)));

constexpr int Bc = 2, Sc = 2048, Dc = 1024, Hc = 16, DHc = 64;

__device__ __forceinline__ u16 f2bf(float f) {
  uint32_t u = __builtin_bit_cast(uint32_t, f);
  u += 0x7fffu + ((u >> 16) & 1u);
  return (u16)(u >> 16);
}
__device__ __forceinline__ float bf2f(u16 h) {
  uint32_t u = ((uint32_t)h) << 16;
  return __builtin_bit_cast(float, u);
}
__device__ __forceinline__ f32x4 mfma16(bf16x8 a, bf16x8 b, f32x4 c) {
  return __builtin_amdgcn_mfma_f32_16x16x32_bf16(a, b, c, 0, 0, 0);
}
__device__ __forceinline__ uint4 pack8(const float4& a, const float4& b) {
  uint4 o;
  o.x = (uint32_t)f2bf(a.x) | ((uint32_t)f2bf(a.y) << 16);
  o.y = (uint32_t)f2bf(a.z) | ((uint32_t)f2bf(a.w) << 16);
  o.z = (uint32_t)f2bf(b.x) | ((uint32_t)f2bf(b.y) << 16);
  o.w = (uint32_t)f2bf(b.z) | ((uint32_t)f2bf(b.w) << 16);
  return o;
}

// ---------------- bf16 GEMM, 512 threads (8 waves: 2M x 4N, 64x32 per wave).
// A may be f32 (converted during staging); B is f32.
// C[m][n] = (sum_k A[m][k]*B[n][k] + bias[n]) * scale
template <bool AF32>
__global__ __launch_bounds__(512) void gemm_bt(
    const void* __restrict__ Av, const float* __restrict__ Bw,
    const float* __restrict__ bias, int M, int N, int K, float scale,
    u16* __restrict__ outb, float* __restrict__ outf,
    int DHn, long strideB, long strideS, long strideH, long strideE) {
  constexpr int LDK = 40;  // 32 + 8 pad -> conflict-free ds_read_b128
  __shared__ u16 As[128 * LDK];
  __shared__ u16 Bs[128 * LDK];
  const int tid = threadIdx.x;
  const int lane = tid & 63;
  const int w = tid >> 6, wm = w >> 2, wn = w & 3;
  const int lo = lane & 15, hi = lane >> 4;
  const int m0 = blockIdx.y * 128, n0 = blockIdx.x * 128;
  const f32x4 vzero = {0.f, 0.f, 0.f, 0.f};

  f32x4 acc[4][2];
  #pragma unroll
  for (int i = 0; i < 4; ++i)
    #pragma unroll
    for (int j = 0; j < 2; ++j) acc[i][j] = vzero;

  for (int k0 = 0; k0 < K; k0 += 32) {
    {  // staging: 512 threads x 8 elems = 128 rows x 32 cols in one shot
      const int e = tid * 8;
      const int r = e >> 5, c = e & 31;
      if (AF32) {
        const float* Af = (const float*)Av;
        const float4 u0 = *reinterpret_cast<const float4*>(&Af[(long)(m0 + r) * K + k0 + c]);
        const float4 u1 = *reinterpret_cast<const float4*>(&Af[(long)(m0 + r) * K + k0 + c + 4]);
        *reinterpret_cast<uint4*>(&As[r * LDK + c]) = pack8(u0, u1);
      } else {
        const u16* Ab = (const u16*)Av;
        *reinterpret_cast<uint4*>(&As[r * LDK + c]) =
            *reinterpret_cast<const uint4*>(&Ab[(long)(m0 + r) * K + k0 + c]);
      }
      int nr = n0 + r; nr = nr < N ? nr : N - 1;  // clamp (vproj N=64)
      const float4 w0 = *reinterpret_cast<const float4*>(&Bw[(long)nr * K + k0 + c]);
      const float4 w1 = *reinterpret_cast<const float4*>(&Bw[(long)nr * K + k0 + c + 4]);
      *reinterpret_cast<uint4*>(&Bs[r * LDK + c]) = pack8(w0, w1);
    }
    __syncthreads();
    bf16x8 af[4], bfr[2];
    #pragma unroll
    for (int mi = 0; mi < 4; ++mi)
      af[mi] = *reinterpret_cast<const bf16x8*>(&As[(wm * 64 + mi * 16 + lo) * LDK + hi * 8]);
    #pragma unroll
    for (int nj = 0; nj < 2; ++nj)
      bfr[nj] = *reinterpret_cast<const bf16x8*>(&Bs[(wn * 32 + nj * 16 + lo) * LDK + hi * 8]);
    #pragma unroll
    for (int mi = 0; mi < 4; ++mi)
      #pragma unroll
      for (int nj = 0; nj < 2; ++nj)
        acc[mi][nj] = mfma16(af[mi], bfr[nj], acc[mi][nj]);
    __syncthreads();
  }

  #pragma unroll
  for (int nj = 0; nj < 2; ++nj) {
    const int n = n0 + wn * 32 + nj * 16 + lo;
    if (n >= N) continue;
    const float bb = bias ? bias[n] : 0.f;
    const int hh = n / DHn, ee = n % DHn;
    #pragma unroll
    for (int mi = 0; mi < 4; ++mi) {
      #pragma unroll
      for (int r = 0; r < 4; ++r) {
        const int mm = m0 + wm * 64 + mi * 16 + hi * 4 + r;
        const int bidx = mm >> 11, ss = mm & 2047;  // S = 2048
        const long idx = bidx * strideB + ss * strideS + hh * strideH + ee * strideE;
        const float val = (acc[mi][nj][r] + bb) * scale;
        if (outf) outf[idx] = val;
        else outb[idx] = f2bf(val);
      }
    }
  }
}

// ---------------- fused causal attention, work-balanced strip pairs (r3 verbatim)
// Each wave: strips idx and 127-idx (16 rows each) => identical work per wave.
// qh,kh: [B,H,S,DH] bf16 (qh pre-scaled by 1/8). vT: [B,DH,S] bf16.
// outh: [B,H,S,DH] bf16. attn_out: [B,S,H,S] f32.
__global__ __launch_bounds__(256) void attn_fused(
    const u16* __restrict__ qh, const u16* __restrict__ kh,
    const u16* __restrict__ vT, u16* __restrict__ outh,
    float* __restrict__ attn_out) {
  __shared__ u16 plds[4 * 16 * 80];  // per-wave transpose buffer, pitch 80 (conflict-free)
  const int tid = threadIdx.x;
  const int lane = tid & 63, w = tid >> 6;
  const int lo = lane & 15, hi = lane >> 4;
  const int blk = blockIdx.x;
  const int sb = blk & 15, h = (blk >> 4) & 15, b = blk >> 8;
  const long bh = (long)(b * Hc + h) * Sc;
  const long rowstride = (long)Hc * Sc;  // 32768
  float* aout = attn_out + (long)b * Sc * rowstride + (long)h * Sc;
  u16* pbuf = &plds[w * 16 * 80];
  const f32x4 vzero = {0.f, 0.f, 0.f, 0.f};
  const int idx = sb * 4 + w;  // 0..63

  #pragma unroll 1
  for (int sp = 0; sp < 2; ++sp) {
    const int strip = sp ? 127 - idx : idx;
    const int s0 = strip * 16;
    const int smax = s0 + 15;
    const int send = (smax / 64 + 1) * 64;  // end of live region, 64-aligned
    const int srow = s0 + hi * 4;

    bf16x8 qa0, qa1;
    {
      const u16* qp = &qh[(bh + s0 + lo) * DHc];
      qa0 = *reinterpret_cast<const bf16x8*>(&qp[hi * 8]);
      qa1 = *reinterpret_cast<const bf16x8*>(&qp[32 + hi * 8]);
    }

    // ---- pass 1: online max/sum, 64 cols per iteration ----
    float mr[4], lr[4];
    #pragma unroll
    for (int r = 0; r < 4; ++r) { mr[r] = -1e30f; lr[r] = 0.f; }

    for (int t0 = 0; t0 < send; t0 += 64) {
      f32x4 z[4];
      #pragma unroll
      for (int c = 0; c < 4; ++c) {
        const u16* kp = &kh[(bh + t0 + c * 16 + lo) * DHc];
        bf16x8 kb0 = *reinterpret_cast<const bf16x8*>(&kp[hi * 8]);
        bf16x8 kb1 = *reinterpret_cast<const bf16x8*>(&kp[32 + hi * 8]);
        f32x4 zz = mfma16(qa0, kb0, vzero);
        z[c] = mfma16(qa1, kb1, zz);
      }
      #pragma unroll
      for (int r = 0; r < 4; ++r) {
        const int s = srow + r;
        float mt = -1e30f;
        #pragma unroll
        for (int c = 0; c < 4; ++c) {
          const bool okc = (t0 + c * 16 + lo) <= s;
          mt = fmaxf(mt, okc ? z[c][r] : -1e30f);
        }
        const float mn = fmaxf(mr[r], mt);
        float sum = 0.f;
        #pragma unroll
        for (int c = 0; c < 4; ++c) {
          const bool okc = (t0 + c * 16 + lo) <= s;
          sum += okc ? __expf(z[c][r] - mn) : 0.f;
        }
        lr[r] = lr[r] * __expf(mr[r] - mn) + sum;
        mr[r] = mn;
      }
    }
    // butterfly reduce across the 16 column-lanes
    #pragma unroll
    for (int r = 0; r < 4; ++r) {
      #pragma unroll
      for (int dd = 1; dd < 16; dd <<= 1) {
        const float mo = __shfl_xor(mr[r], dd);
        const float lx = __shfl_xor(lr[r], dd);
        const float mn = fmaxf(mr[r], mo);
        lr[r] = lr[r] * __expf(mr[r] - mn) + lx * __expf(mo - mn);
        mr[r] = mn;
      }
      lr[r] = 1.f / lr[r];  // inverse denom
    }

    // ---- pass 2: recompute, store normalized p, accumulate PV ----
    f32x4 acco[4];
    #pragma unroll
    for (int eb = 0; eb < 4; ++eb) acco[eb] = vzero;

    for (int t0 = 0; t0 < send; t0 += 64) {
      f32x4 z[4];
      #pragma unroll
      for (int c = 0; c < 4; ++c) {
        const u16* kp = &kh[(bh + t0 + c * 16 + lo) * DHc];
        bf16x8 kb0 = *reinterpret_cast<const bf16x8*>(&kp[hi * 8]);
        bf16x8 kb1 = *reinterpret_cast<const bf16x8*>(&kp[32 + hi * 8]);
        f32x4 zz = mfma16(qa0, kb0, vzero);
        z[c] = mfma16(qa1, kb1, zz);
      }
      #pragma unroll
      for (int r = 0; r < 4; ++r) {
        const int s = srow + r;
        float* rp = aout + (long)s * rowstride + t0 + lo;
        #pragma unroll
        for (int c = 0; c < 4; ++c) {
          const bool okc = (t0 + c * 16 + lo) <= s;
          const float p = okc ? __expf(z[c][r] - mr[r]) * lr[r] : 0.f;
          rp[c * 16] = p;
          pbuf[(hi * 4 + r) * 80 + c * 16 + lo] = f2bf(p);
        }
      }
      asm volatile("s_waitcnt lgkmcnt(0)" ::: "memory");
      __builtin_amdgcn_sched_barrier(0);
      bf16x8 pa0 = *reinterpret_cast<const bf16x8*>(&pbuf[lo * 80 + hi * 8]);
      bf16x8 pa1 = *reinterpret_cast<const bf16x8*>(&pbuf[lo * 80 + 32 + hi * 8]);
      const u16* vp = &vT[((long)b * DHc + lo) * Sc + t0 + hi * 8];
      #pragma unroll
      for (int eb = 0; eb < 4; ++eb) {
        bf16x8 vb0 = *reinterpret_cast<const bf16x8*>(&vp[(long)eb * 16 * Sc]);
        bf16x8 vb1 = *reinterpret_cast<const bf16x8*>(&vp[(long)eb * 16 * Sc + 32]);
        acco[eb] = mfma16(pa0, vb0, acco[eb]);
        acco[eb] = mfma16(pa1, vb1, acco[eb]);
      }
    }

    // ---- epilogue: outh store + zero-fill masked region ----
    #pragma unroll
    for (int eb = 0; eb < 4; ++eb)
      #pragma unroll
      for (int r = 0; r < 4; ++r)
        outh[(bh + srow + r) * DHc + eb * 16 + lo] = f2bf(acco[eb][r]);

    const float4 z4 = {0.f, 0.f, 0.f, 0.f};
    for (int t0 = send; t0 < Sc; t0 += 64) {
      #pragma unroll
      for (int r = 0; r < 4; ++r)
        *reinterpret_cast<float4*>(aout + (long)(srow + r) * rowstride + t0 + lo * 4) = z4;
    }
  }
}

// ---------------- mean over heads
__global__ __launch_bounds__(256) void mean_kernel(const u16* __restrict__ outh,
                                                   u16* __restrict__ meanb) {
  const int idx = blockIdx.x * 256 + threadIdx.x;  // 32768 threads
  const int bs = idx >> 3;
  const int e0 = (idx & 7) * 8;
  const int b = bs >> 11, s = bs & 2047;
  float acc[8];
  #pragma unroll
  for (int j = 0; j < 8; ++j) acc[j] = 0.f;
  for (int h = 0; h < Hc; ++h) {
    alignas(16) u16 tmp[8];
    *reinterpret_cast<uint4*>(tmp) =
        *reinterpret_cast<const uint4*>(&outh[((long)(b * Hc + h) * Sc + s) * DHc + e0]);
    #pragma unroll
    for (int j = 0; j < 8; ++j) acc[j] += bf2f(tmp[j]);
  }
  alignas(16) u16 o[8];
  #pragma unroll
  for (int j = 0; j < 8; ++j) o[j] = f2bf(acc[j] * 0.0625f);
  *reinterpret_cast<uint4*>(&meanb[(long)bs * DHc + e0]) = *reinterpret_cast<const uint4*>(o);
}

extern "C" void kernel_launch(void* const* d_in, const int* in_sizes, int n_in,
                              void* d_out, int out_size, void* d_ws, size_t ws_size,
                              hipStream_t stream) {
  (void)in_sizes; (void)n_in; (void)out_size; (void)ws_size;
  const float* q  = (const float*)d_in[0];
  const float* k  = (const float*)d_in[1];
  const float* v  = (const float*)d_in[2];
  const float* Wv = (const float*)d_in[4];
  const float* bv = (const float*)d_in[5];
  const float* Wq = (const float*)d_in[6];
  const float* bq = (const float*)d_in[7];
  const float* Wk = (const float*)d_in[8];
  const float* bk = (const float*)d_in[9];
  const float* Wo = (const float*)d_in[10];

  char* ws = (char*)d_ws;
  u16* qhb   = (u16*)(ws + 0);          // 8 MB  [B,H,S,DH]
  u16* khb   = (u16*)(ws + 8388608);    // 8 MB
  u16* vTb   = (u16*)(ws + 16777216);   // 512 KB [B,DH,S]
  u16* outh  = (u16*)(ws + 17301504);   // 8 MB  [B,H,S,DH]
  u16* meanb = (u16*)(ws + 25690112);   // 512 KB

  float* outp  = (float*)d_out;
  float* attnp = (float*)d_out + (long)Bc * Sc * Dc;

  const int M = Bc * Sc;  // 4096
  gemm_bt<true><<<dim3(8, 32), 512, 0, stream>>>(q, Wq, bq, M, 1024, 1024, 0.125f,
      qhb, nullptr, 64, 2097152L, 64L, 131072L, 1L);
  gemm_bt<true><<<dim3(8, 32), 512, 0, stream>>>(k, Wk, bk, M, 1024, 1024, 1.0f,
      khb, nullptr, 64, 2097152L, 64L, 131072L, 1L);
  gemm_bt<true><<<dim3(1, 32), 512, 0, stream>>>(v, Wv, bv, M, 64, 1024, 1.0f,
      vTb, nullptr, 64, 131072L, 1L, 0L, 2048L);

  attn_fused<<<512, 256, 0, stream>>>(qhb, khb, vTb, outh, attnp);

  mean_kernel<<<128, 256, 0, stream>>>(outh, meanb);

  gemm_bt<false><<<dim3(8, 32), 512, 0, stream>>>(meanb, Wo, nullptr, M, 1024, 64, 1.0f,
      nullptr, outp, 1024, 2097152L, 1024L, 0L, 1L);
}

// Round 9
// 363.473 us; speedup vs baseline: 1.1670x; 1.1670x over previous
//
#include <hip/hip_runtime.h>
#include <cstdint>

typedef unsigned short u16;
typedef __bf16 bf16x8 __attribute__((ext_vector_type(8)));
typedef float f32x4 __attribute__((ext_vector_type(4)));

constexpr int Bc = 2, Sc = 2048, Dc = 1024, Hc = 16, DHc = 64;

__device__ __forceinline__ u16 f2bf(float f) {
  uint32_t u = __builtin_bit_cast(uint32_t, f);
  u += 0x7fffu + ((u >> 16) & 1u);
  return (u16)(u >> 16);
}
__device__ __forceinline__ float bf2f(u16 h) {
  uint32_t u = ((uint32_t)h) << 16;
  return __builtin_bit_cast(float, u);
}
__device__ __forceinline__ f32x4 mfma16(bf16x8 a, bf16x8 b, f32x4 c) {
  return __builtin_amdgcn_mfma_f32_16x16x32_bf16(a, b, c, 0, 0, 0);
}
// async global->LDS, 16B per lane; LDS base must be wave-uniform, global addr per-lane
__device__ __forceinline__ void gload16(const void* g, void* l) {
  __builtin_amdgcn_global_load_lds((const uint32_t*)g, (uint32_t*)l, 16, 0, 0);
}

// ---------------- f32 -> bf16 conversion, 4 elems/thread ----------------
__global__ __launch_bounds__(256) void cvt_kernel(const float* __restrict__ in,
                                                  u16* __restrict__ out, int n4) {
  int i = blockIdx.x * 256 + threadIdx.x;
  if (i >= n4) return;
  float4 v = reinterpret_cast<const float4*>(in)[i];
  ushort4 o;
  o.x = f2bf(v.x); o.y = f2bf(v.y); o.z = f2bf(v.z); o.w = f2bf(v.w);
  reinterpret_cast<ushort4*>(out)[i] = o;
}

// ---------------- bf16 GEMM, global_load_lds staging (m97 structure)
// C[m][n] = (sum_k A[m][k]*B[n][k] + bias[n]) * scale
// LDS is LINEAR [128][32] (gload_lds forbids padding). For N<128 the B staging
// reads rows up to 127 from adjacent (defined) ws memory; those accumulators
// are discarded by the n>=N epilogue guard.
__global__ __launch_bounds__(256) void gemm_bt(
    const u16* __restrict__ A, const u16* __restrict__ Bw,
    const float* __restrict__ bias, int M, int N, int K, float scale,
    u16* __restrict__ outb, float* __restrict__ outf,
    int DHn, long strideB, long strideS, long strideH, long strideE) {
  __shared__ u16 As[128 * 32];
  __shared__ u16 Bs[128 * 32];
  const int tid = threadIdx.x;
  const int lane = tid & 63;
  const int w = tid >> 6, wm = w >> 1, wn = w & 1;
  const int lo = lane & 15, hi = lane >> 4;
  const int m0 = blockIdx.y * 128, n0 = blockIdx.x * 128;
  const int r16 = lane >> 2;        // row within 16-row group
  const int c8 = (lane & 3) * 8;    // u16 col offset (4 lanes x 16B = one 64B row)
  const f32x4 vzero = {0.f, 0.f, 0.f, 0.f};

  f32x4 acc[4][4];
  #pragma unroll
  for (int i = 0; i < 4; ++i)
    #pragma unroll
    for (int j = 0; j < 4; ++j) acc[i][j] = vzero;

  for (int k0 = 0; k0 < K; k0 += 32) {
    #pragma unroll
    for (int it = 0; it < 2; ++it) {
      const int rg = w * 2 + it;      // wave-uniform 16-row group 0..7
      const int row = rg * 16 + r16;
      gload16(&A[(long)(m0 + row) * K + k0 + c8], &As[rg * 512]);
      gload16(&Bw[(long)(n0 + row) * K + k0 + c8], &Bs[rg * 512]);
    }
    __syncthreads();  // drains vmcnt (gload_lds) + lgkm
    bf16x8 af[4], bfr[4];
    #pragma unroll
    for (int mi = 0; mi < 4; ++mi)
      af[mi] = *reinterpret_cast<const bf16x8*>(&As[(wm * 64 + mi * 16 + lo) * 32 + hi * 8]);
    #pragma unroll
    for (int nj = 0; nj < 4; ++nj)
      bfr[nj] = *reinterpret_cast<const bf16x8*>(&Bs[(wn * 64 + nj * 16 + lo) * 32 + hi * 8]);
    #pragma unroll
    for (int mi = 0; mi < 4; ++mi)
      #pragma unroll
      for (int nj = 0; nj < 4; ++nj)
        acc[mi][nj] = mfma16(af[mi], bfr[nj], acc[mi][nj]);
    __syncthreads();
  }

  #pragma unroll
  for (int nj = 0; nj < 4; ++nj) {
    const int n = n0 + wn * 64 + nj * 16 + lo;
    if (n >= N) continue;
    const float bb = bias ? bias[n] : 0.f;
    const int hh = n / DHn, ee = n % DHn;
    #pragma unroll
    for (int mi = 0; mi < 4; ++mi) {
      #pragma unroll
      for (int r = 0; r < 4; ++r) {
        const int mm = m0 + wm * 64 + mi * 16 + hi * 4 + r;
        const int bidx = mm >> 11, ss = mm & 2047;  // S = 2048
        const long idx = bidx * strideB + ss * strideS + hh * strideH + ee * strideE;
        const float val = (acc[mi][nj][r] + bb) * scale;
        if (outf) outf[idx] = val;
        else outb[idx] = f2bf(val);
      }
    }
  }
}

// ---------------- fused causal attention, work-balanced strip pairs (r3 verbatim)
// Each wave: strips idx and 127-idx (16 rows each) => identical work per wave.
// qh,kh: [B,H,S,DH] bf16 (qh pre-scaled by 1/8). vT: [B,DH,S] bf16.
// outh: [B,H,S,DH] bf16. attn_out: [B,S,H,S] f32.
__global__ __launch_bounds__(256) void attn_fused(
    const u16* __restrict__ qh, const u16* __restrict__ kh,
    const u16* __restrict__ vT, u16* __restrict__ outh,
    float* __restrict__ attn_out) {
  __shared__ u16 plds[4 * 16 * 80];  // per-wave transpose buffer, pitch 80 (conflict-free)
  const int tid = threadIdx.x;
  const int lane = tid & 63, w = tid >> 6;
  const int lo = lane & 15, hi = lane >> 4;
  const int blk = blockIdx.x;
  const int sb = blk & 15, h = (blk >> 4) & 15, b = blk >> 8;
  const long bh = (long)(b * Hc + h) * Sc;
  const long rowstride = (long)Hc * Sc;  // 32768
  float* aout = attn_out + (long)b * Sc * rowstride + (long)h * Sc;
  u16* pbuf = &plds[w * 16 * 80];
  const f32x4 vzero = {0.f, 0.f, 0.f, 0.f};
  const int idx = sb * 4 + w;  // 0..63

  #pragma unroll 1
  for (int sp = 0; sp < 2; ++sp) {
    const int strip = sp ? 127 - idx : idx;
    const int s0 = strip * 16;
    const int smax = s0 + 15;
    const int send = (smax / 64 + 1) * 64;  // end of live region, 64-aligned
    const int srow = s0 + hi * 4;

    bf16x8 qa0, qa1;
    {
      const u16* qp = &qh[(bh + s0 + lo) * DHc];
      qa0 = *reinterpret_cast<const bf16x8*>(&qp[hi * 8]);
      qa1 = *reinterpret_cast<const bf16x8*>(&qp[32 + hi * 8]);
    }

    // ---- pass 1: online max/sum, 64 cols per iteration ----
    float mr[4], lr[4];
    #pragma unroll
    for (int r = 0; r < 4; ++r) { mr[r] = -1e30f; lr[r] = 0.f; }

    for (int t0 = 0; t0 < send; t0 += 64) {
      f32x4 z[4];
      #pragma unroll
      for (int c = 0; c < 4; ++c) {
        const u16* kp = &kh[(bh + t0 + c * 16 + lo) * DHc];
        bf16x8 kb0 = *reinterpret_cast<const bf16x8*>(&kp[hi * 8]);
        bf16x8 kb1 = *reinterpret_cast<const bf16x8*>(&kp[32 + hi * 8]);
        f32x4 zz = mfma16(qa0, kb0, vzero);
        z[c] = mfma16(qa1, kb1, zz);
      }
      #pragma unroll
      for (int r = 0; r < 4; ++r) {
        const int s = srow + r;
        float mt = -1e30f;
        #pragma unroll
        for (int c = 0; c < 4; ++c) {
          const bool okc = (t0 + c * 16 + lo) <= s;
          mt = fmaxf(mt, okc ? z[c][r] : -1e30f);
        }
        const float mn = fmaxf(mr[r], mt);
        float sum = 0.f;
        #pragma unroll
        for (int c = 0; c < 4; ++c) {
          const bool okc = (t0 + c * 16 + lo) <= s;
          sum += okc ? __expf(z[c][r] - mn) : 0.f;
        }
        lr[r] = lr[r] * __expf(mr[r] - mn) + sum;
        mr[r] = mn;
      }
    }
    // butterfly reduce across the 16 column-lanes
    #pragma unroll
    for (int r = 0; r < 4; ++r) {
      #pragma unroll
      for (int dd = 1; dd < 16; dd <<= 1) {
        const float mo = __shfl_xor(mr[r], dd);
        const float lx = __shfl_xor(lr[r], dd);
        const float mn = fmaxf(mr[r], mo);
        lr[r] = lr[r] * __expf(mr[r] - mn) + lx * __expf(mo - mn);
        mr[r] = mn;
      }
      lr[r] = 1.f / lr[r];  // inverse denom
    }

    // ---- pass 2: recompute, store normalized p, accumulate PV ----
    f32x4 acco[4];
    #pragma unroll
    for (int eb = 0; eb < 4; ++eb) acco[eb] = vzero;

    for (int t0 = 0; t0 < send; t0 += 64) {
      f32x4 z[4];
      #pragma unroll
      for (int c = 0; c < 4; ++c) {
        const u16* kp = &kh[(bh + t0 + c * 16 + lo) * DHc];
        bf16x8 kb0 = *reinterpret_cast<const bf16x8*>(&kp[hi * 8]);
        bf16x8 kb1 = *reinterpret_cast<const bf16x8*>(&kp[32 + hi * 8]);
        f32x4 zz = mfma16(qa0, kb0, vzero);
        z[c] = mfma16(qa1, kb1, zz);
      }
      #pragma unroll
      for (int r = 0; r < 4; ++r) {
        const int s = srow + r;
        float* rp = aout + (long)s * rowstride + t0 + lo;
        #pragma unroll
        for (int c = 0; c < 4; ++c) {
          const bool okc = (t0 + c * 16 + lo) <= s;
          const float p = okc ? __expf(z[c][r] - mr[r]) * lr[r] : 0.f;
          rp[c * 16] = p;
          pbuf[(hi * 4 + r) * 80 + c * 16 + lo] = f2bf(p);
        }
      }
      asm volatile("s_waitcnt lgkmcnt(0)" ::: "memory");
      __builtin_amdgcn_sched_barrier(0);
      bf16x8 pa0 = *reinterpret_cast<const bf16x8*>(&pbuf[lo * 80 + hi * 8]);
      bf16x8 pa1 = *reinterpret_cast<const bf16x8*>(&pbuf[lo * 80 + 32 + hi * 8]);
      const u16* vp = &vT[((long)b * DHc + lo) * Sc + t0 + hi * 8];
      #pragma unroll
      for (int eb = 0; eb < 4; ++eb) {
        bf16x8 vb0 = *reinterpret_cast<const bf16x8*>(&vp[(long)eb * 16 * Sc]);
        bf16x8 vb1 = *reinterpret_cast<const bf16x8*>(&vp[(long)eb * 16 * Sc + 32]);
        acco[eb] = mfma16(pa0, vb0, acco[eb]);
        acco[eb] = mfma16(pa1, vb1, acco[eb]);
      }
    }

    // ---- epilogue: outh store + zero-fill masked region ----
    #pragma unroll
    for (int eb = 0; eb < 4; ++eb)
      #pragma unroll
      for (int r = 0; r < 4; ++r)
        outh[(bh + srow + r) * DHc + eb * 16 + lo] = f2bf(acco[eb][r]);

    const float4 z4 = {0.f, 0.f, 0.f, 0.f};
    for (int t0 = send; t0 < Sc; t0 += 64) {
      #pragma unroll
      for (int r = 0; r < 4; ++r)
        *reinterpret_cast<float4*>(aout + (long)(srow + r) * rowstride + t0 + lo * 4) = z4;
    }
  }
}

// ---------------- mean over heads
__global__ __launch_bounds__(256) void mean_kernel(const u16* __restrict__ outh,
                                                   u16* __restrict__ meanb) {
  const int idx = blockIdx.x * 256 + threadIdx.x;  // 32768 threads
  const int bs = idx >> 3;
  const int e0 = (idx & 7) * 8;
  const int b = bs >> 11, s = bs & 2047;
  float acc[8];
  #pragma unroll
  for (int j = 0; j < 8; ++j) acc[j] = 0.f;
  for (int h = 0; h < Hc; ++h) {
    alignas(16) u16 tmp[8];
    *reinterpret_cast<uint4*>(tmp) =
        *reinterpret_cast<const uint4*>(&outh[((long)(b * Hc + h) * Sc + s) * DHc + e0]);
    #pragma unroll
    for (int j = 0; j < 8; ++j) acc[j] += bf2f(tmp[j]);
  }
  alignas(16) u16 o[8];
  #pragma unroll
  for (int j = 0; j < 8; ++j) o[j] = f2bf(acc[j] * 0.0625f);
  *reinterpret_cast<uint4*>(&meanb[(long)bs * DHc + e0]) = *reinterpret_cast<const uint4*>(o);
}

extern "C" void kernel_launch(void* const* d_in, const int* in_sizes, int n_in,
                              void* d_out, int out_size, void* d_ws, size_t ws_size,
                              hipStream_t stream) {
  (void)in_sizes; (void)n_in; (void)out_size; (void)ws_size;
  const float* q  = (const float*)d_in[0];
  const float* k  = (const float*)d_in[1];
  const float* v  = (const float*)d_in[2];
  const float* Wv = (const float*)d_in[4];
  const float* bv = (const float*)d_in[5];
  const float* Wq = (const float*)d_in[6];
  const float* bq = (const float*)d_in[7];
  const float* Wk = (const float*)d_in[8];
  const float* bk = (const float*)d_in[9];
  const float* Wo = (const float*)d_in[10];

  char* ws = (char*)d_ws;
  u16* qbf   = (u16*)(ws + 0);          // 8.0 MB
  u16* kbf   = (u16*)(ws + 8388608);
  u16* vbf   = (u16*)(ws + 16777216);
  u16* Wqbf  = (u16*)(ws + 25165824);   // 2 MB
  u16* Wkbf  = (u16*)(ws + 27262976);
  u16* Wvbf  = (u16*)(ws + 29360128);   // 128 KB (B staging may read into Wobf: defined)
  u16* Wobf  = (u16*)(ws + 29491200);
  u16* qhb   = (u16*)(ws + 29622272);   // 8 MB  [B,H,S,DH]
  u16* khb   = (u16*)(ws + 38010880);
  u16* vTb   = (u16*)(ws + 46399488);   // 512 KB [B,DH,S]
  u16* outh  = (u16*)(ws + 46923776);   // 8 MB  [B,H,S,DH]
  u16* meanb = (u16*)(ws + 55312384);   // 512 KB

  float* outp  = (float*)d_out;
  float* attnp = (float*)d_out + (long)Bc * Sc * Dc;

  auto cvt = [&](const float* in, u16* out, int n) {
    cvt_kernel<<<(n / 4 + 255) / 256, 256, 0, stream>>>(in, out, n / 4);
  };
  cvt(q,  qbf,  Bc * Sc * Dc);
  cvt(k,  kbf,  Bc * Sc * Dc);
  cvt(v,  vbf,  Bc * Sc * Dc);
  cvt(Wq, Wqbf, Hc * DHc * Dc);
  cvt(Wk, Wkbf, Hc * DHc * Dc);
  cvt(Wv, Wvbf, DHc * Dc);
  cvt(Wo, Wobf, Dc * DHc);

  const int M = Bc * Sc;  // 4096
  gemm_bt<<<dim3(8, 32), 256, 0, stream>>>(qbf, Wqbf, bq, M, 1024, 1024, 0.125f,
      qhb, nullptr, 64, 2097152L, 64L, 131072L, 1L);
  gemm_bt<<<dim3(8, 32), 256, 0, stream>>>(kbf, Wkbf, bk, M, 1024, 1024, 1.0f,
      khb, nullptr, 64, 2097152L, 64L, 131072L, 1L);
  gemm_bt<<<dim3(1, 32), 256, 0, stream>>>(vbf, Wvbf, bv, M, 64, 1024, 1.0f,
      vTb, nullptr, 64, 131072L, 1L, 0L, 2048L);

  attn_fused<<<512, 256, 0, stream>>>(qhb, khb, vTb, outh, attnp);

  mean_kernel<<<128, 256, 0, stream>>>(outh, meanb);

  gemm_bt<<<dim3(8, 32), 256, 0, stream>>>(meanb, Wobf, nullptr, M, 1024, 64, 1.0f,
      nullptr, outp, 1024, 2097152L, 1024L, 0L, 1L);
}

// Round 11
// 337.825 us; speedup vs baseline: 1.2556x; 1.0759x over previous
//
#include <hip/hip_runtime.h>
#include <cstdint>
#include <math.h>

typedef unsigned short u16;
typedef __bf16 bf16x8 __attribute__((ext_vector_type(8)));
typedef float f32x4 __attribute__((ext_vector_type(4)));

constexpr int Bc = 2, Sc = 2048, Dc = 1024, Hc = 16, DHc = 64;

__device__ __forceinline__ u16 f2bf(float f) {
  uint32_t u = __builtin_bit_cast(uint32_t, f);
  u += 0x7fffu + ((u >> 16) & 1u);
  return (u16)(u >> 16);
}
__device__ __forceinline__ float bf2f(u16 h) {
  uint32_t u = ((uint32_t)h) << 16;
  return __builtin_bit_cast(float, u);
}
__device__ __forceinline__ f32x4 mfma16(bf16x8 a, bf16x8 b, f32x4 c) {
  return __builtin_amdgcn_mfma_f32_16x16x32_bf16(a, b, c, 0, 0, 0);
}
// async global->LDS, 16B per lane; LDS base must be wave-uniform, global addr per-lane
__device__ __forceinline__ void gload16(const void* g, void* l) {
  __builtin_amdgcn_global_load_lds((const uint32_t*)g, (uint32_t*)l, 16, 0, 0);
}

// ---------------- f32 -> bf16 conversion, 4 elems/thread ----------------
__global__ __launch_bounds__(256) void cvt_kernel(const float* __restrict__ in,
                                                  u16* __restrict__ out, int n4) {
  int i = blockIdx.x * 256 + threadIdx.x;
  if (i >= n4) return;
  float4 v = reinterpret_cast<const float4*>(in)[i];
  ushort4 o;
  o.x = f2bf(v.x); o.y = f2bf(v.y); o.z = f2bf(v.z); o.w = f2bf(v.w);
  reinterpret_cast<ushort4*>(out)[i] = o;
}

// ---------------- bf16 GEMM, global_load_lds staging (m97 structure)
// C[m][n] = (sum_k A[m][k]*B[n][k] + bias[n]) * scale
__global__ __launch_bounds__(256) void gemm_bt(
    const u16* __restrict__ A, const u16* __restrict__ Bw,
    const float* __restrict__ bias, int M, int N, int K, float scale,
    u16* __restrict__ outb, float* __restrict__ outf,
    int DHn, long strideB, long strideS, long strideH, long strideE) {
  __shared__ u16 As[128 * 32];
  __shared__ u16 Bs[128 * 32];
  const int tid = threadIdx.x;
  const int lane = tid & 63;
  const int w = tid >> 6, wm = w >> 1, wn = w & 1;
  const int lo = lane & 15, hi = lane >> 4;
  const int m0 = blockIdx.y * 128, n0 = blockIdx.x * 128;
  const int r16 = lane >> 2;        // row within 16-row group
  const int c8 = (lane & 3) * 8;    // u16 col offset (4 lanes x 16B = one 64B row)
  const f32x4 vzero = {0.f, 0.f, 0.f, 0.f};

  f32x4 acc[4][4];
  #pragma unroll
  for (int i = 0; i < 4; ++i)
    #pragma unroll
    for (int j = 0; j < 4; ++j) acc[i][j] = vzero;

  for (int k0 = 0; k0 < K; k0 += 32) {
    #pragma unroll
    for (int it = 0; it < 2; ++it) {
      const int rg = w * 2 + it;      // wave-uniform 16-row group 0..7
      const int row = rg * 16 + r16;
      gload16(&A[(long)(m0 + row) * K + k0 + c8], &As[rg * 512]);
      gload16(&Bw[(long)(n0 + row) * K + k0 + c8], &Bs[rg * 512]);
    }
    __syncthreads();  // drains vmcnt (gload_lds) + lgkm
    bf16x8 af[4], bfr[4];
    #pragma unroll
    for (int mi = 0; mi < 4; ++mi)
      af[mi] = *reinterpret_cast<const bf16x8*>(&As[(wm * 64 + mi * 16 + lo) * 32 + hi * 8]);
    #pragma unroll
    for (int nj = 0; nj < 4; ++nj)
      bfr[nj] = *reinterpret_cast<const bf16x8*>(&Bs[(wn * 64 + nj * 16 + lo) * 32 + hi * 8]);
    #pragma unroll
    for (int mi = 0; mi < 4; ++mi)
      #pragma unroll
      for (int nj = 0; nj < 4; ++nj)
        acc[mi][nj] = mfma16(af[mi], bfr[nj], acc[mi][nj]);
    __syncthreads();
  }

  #pragma unroll
  for (int nj = 0; nj < 4; ++nj) {
    const int n = n0 + wn * 64 + nj * 16 + lo;
    if (n >= N) continue;
    const float bb = bias ? bias[n] : 0.f;
    const int hh = n / DHn, ee = n % DHn;
    #pragma unroll
    for (int mi = 0; mi < 4; ++mi) {
      #pragma unroll
      for (int r = 0; r < 4; ++r) {
        const int mm = m0 + wm * 64 + mi * 16 + hi * 4 + r;
        const int bidx = mm >> 11, ss = mm & 2047;  // S = 2048
        const long idx = bidx * strideB + ss * strideS + hh * strideH + ee * strideE;
        const float val = (acc[mi][nj][r] + bb) * scale;
        if (outf) outf[idx] = val;
        else outb[idx] = f2bf(val);
      }
    }
  }
}

// ---------------- fused causal attention, strip pairs, fixed-max softmax
// qh pre-scaled by log2(e)/8 -> exp2 domain. Fixed offset M0=16:
//   p' = exp2(z-16) (masked), l = sum p', off = 16 + log2(l), p = exp2(z - off).
// Pass 1 (direct layout mfma(Q,K)): p' + l-sum + LDS-transpose + PV (unnormalized).
// Pass 2 (swapped layout mfma(K,Q)): p = exp2(z - off), f32x4 nontemporal stores.
// Each wave: strips idx and 127-idx => identical work per wave (r3 balance).
__global__ __launch_bounds__(256) void attn_fused(
    const u16* __restrict__ qh, const u16* __restrict__ kh,
    const u16* __restrict__ vT, u16* __restrict__ outh,
    float* __restrict__ attn_out) {
  __shared__ u16 plds[4 * 16 * 80];  // per-wave transpose buffer, pitch 80 (conflict-free)
  const int tid = threadIdx.x;
  const int lane = tid & 63, w = tid >> 6;
  const int lo = lane & 15, hi = lane >> 4;
  const int blk = blockIdx.x;
  const int sb = blk & 15, h = (blk >> 4) & 15, b = blk >> 8;
  const long bh = (long)(b * Hc + h) * Sc;
  const long rowstride = (long)Hc * Sc;  // 32768
  float* aout = attn_out + (long)b * Sc * rowstride + (long)h * Sc;
  u16* pbuf = &plds[w * 16 * 80];
  float* poff = (float*)pbuf;  // reused for the 16 per-row normalizers
  const f32x4 vzero = {0.f, 0.f, 0.f, 0.f};
  const int idx = sb * 4 + w;  // 0..63
  const float M0 = 16.f;

  #pragma unroll 1
  for (int sp = 0; sp < 2; ++sp) {
    const int strip = sp ? 127 - idx : idx;
    const int s0 = strip * 16;
    const int smax = s0 + 15;
    const int send = (smax / 64 + 1) * 64;  // end of live region, 64-aligned
    const int srow = s0 + hi * 4;           // pass-1 rows
    const int srow2 = s0 + lo;              // pass-2 row

    bf16x8 qa0, qa1;
    {
      const u16* qp = &qh[(bh + s0 + lo) * DHc];
      qa0 = *reinterpret_cast<const bf16x8*>(&qp[hi * 8]);
      qa1 = *reinterpret_cast<const bf16x8*>(&qp[32 + hi * 8]);
    }

    // ---- pass 1: p' = exp2(z-M0), l-sum, LDS transpose, unnormalized PV ----
    float lr[4];
    f32x4 acco[4];
    #pragma unroll
    for (int r = 0; r < 4; ++r) lr[r] = 0.f;
    #pragma unroll
    for (int eb = 0; eb < 4; ++eb) acco[eb] = vzero;

    for (int t0 = 0; t0 < send; t0 += 64) {
      f32x4 z[4];
      #pragma unroll
      for (int c = 0; c < 4; ++c) {
        const u16* kp = &kh[(bh + t0 + c * 16 + lo) * DHc];
        bf16x8 kb0 = *reinterpret_cast<const bf16x8*>(&kp[hi * 8]);
        bf16x8 kb1 = *reinterpret_cast<const bf16x8*>(&kp[32 + hi * 8]);
        f32x4 zz = mfma16(qa0, kb0, vzero);
        z[c] = mfma16(qa1, kb1, zz);
      }
      const bool full = (t0 + 63 <= s0);
      #pragma unroll
      for (int r = 0; r < 4; ++r) {
        const int s = srow + r;
        #pragma unroll
        for (int c = 0; c < 4; ++c) {
          float e = exp2f(z[c][r] - M0);
          if (!full) e = ((t0 + c * 16 + lo) <= s) ? e : 0.f;
          lr[r] += e;
          pbuf[(hi * 4 + r) * 80 + c * 16 + lo] = f2bf(e);
        }
      }
      asm volatile("s_waitcnt lgkmcnt(0)" ::: "memory");
      __builtin_amdgcn_sched_barrier(0);
      bf16x8 pa0 = *reinterpret_cast<const bf16x8*>(&pbuf[lo * 80 + hi * 8]);
      bf16x8 pa1 = *reinterpret_cast<const bf16x8*>(&pbuf[lo * 80 + 32 + hi * 8]);
      const u16* vp = &vT[((long)b * DHc + lo) * Sc + t0 + hi * 8];
      #pragma unroll
      for (int eb = 0; eb < 4; ++eb) {
        bf16x8 vb0 = *reinterpret_cast<const bf16x8*>(&vp[(long)eb * 16 * Sc]);
        bf16x8 vb1 = *reinterpret_cast<const bf16x8*>(&vp[(long)eb * 16 * Sc + 32]);
        acco[eb] = mfma16(pa0, vb0, acco[eb]);
        acco[eb] = mfma16(pa1, vb1, acco[eb]);
      }
    }
    // sum l across the 16 column-lanes (pure adds: fixed max)
    float inv[4];
    #pragma unroll
    for (int r = 0; r < 4; ++r) {
      #pragma unroll
      for (int dd = 1; dd < 16; dd <<= 1) lr[r] += __shfl_xor(lr[r], dd);
      inv[r] = 1.f / lr[r];
    }
    // publish per-row off = M0 + log2(l) for pass 2 (per-wave LDS, 16 floats)
    if (lo == 0) {
      #pragma unroll
      for (int r = 0; r < 4; ++r) poff[hi * 4 + r] = M0 + __log2f(lr[r]);
    }
    asm volatile("s_waitcnt lgkmcnt(0)" ::: "memory");
    __builtin_amdgcn_sched_barrier(0);
    const float offv = poff[lo];

    // ---- pass 2: swapped-operand z^T, p = exp2(z - off), f32x4 nt stores ----
    for (int t0 = 0; t0 < send; t0 += 64) {
      const bool full = (t0 + 63 <= s0);
      #pragma unroll
      for (int c = 0; c < 4; ++c) {
        const u16* kp = &kh[(bh + t0 + c * 16 + lo) * DHc];
        bf16x8 kb0 = *reinterpret_cast<const bf16x8*>(&kp[hi * 8]);
        bf16x8 kb1 = *reinterpret_cast<const bf16x8*>(&kp[32 + hi * 8]);
        f32x4 zt = mfma16(kb1, qa1, mfma16(kb0, qa0, vzero));
        f32x4 p;
        #pragma unroll
        for (int r = 0; r < 4; ++r) {
          const float e = exp2f(zt[r] - offv);
          p[r] = (full || (t0 + c * 16 + hi * 4 + r <= srow2)) ? e : 0.f;
        }
        __builtin_nontemporal_store(
            p, reinterpret_cast<f32x4*>(aout + (long)srow2 * rowstride + t0 + c * 16 + hi * 4));
      }
    }

    // ---- epilogue: outh store (scaled by 1/l) + nt zero-fill masked region ----
    #pragma unroll
    for (int eb = 0; eb < 4; ++eb)
      #pragma unroll
      for (int r = 0; r < 4; ++r)
        outh[(bh + srow + r) * DHc + eb * 16 + lo] = f2bf(acco[eb][r] * inv[r]);

    const f32x4 z4 = {0.f, 0.f, 0.f, 0.f};
    for (int t0 = send; t0 < Sc; t0 += 64) {
      #pragma unroll
      for (int r = 0; r < 4; ++r)
        __builtin_nontemporal_store(
            z4, reinterpret_cast<f32x4*>(aout + (long)(srow + r) * rowstride + t0 + lo * 4));
    }
  }
}

// ---------------- mean over heads
__global__ __launch_bounds__(256) void mean_kernel(const u16* __restrict__ outh,
                                                   u16* __restrict__ meanb) {
  const int idx = blockIdx.x * 256 + threadIdx.x;  // 32768 threads
  const int bs = idx >> 3;
  const int e0 = (idx & 7) * 8;
  const int b = bs >> 11, s = bs & 2047;
  float acc[8];
  #pragma unroll
  for (int j = 0; j < 8; ++j) acc[j] = 0.f;
  for (int h = 0; h < Hc; ++h) {
    alignas(16) u16 tmp[8];
    *reinterpret_cast<uint4*>(tmp) =
        *reinterpret_cast<const uint4*>(&outh[((long)(b * Hc + h) * Sc + s) * DHc + e0]);
    #pragma unroll
    for (int j = 0; j < 8; ++j) acc[j] += bf2f(tmp[j]);
  }
  alignas(16) u16 o[8];
  #pragma unroll
  for (int j = 0; j < 8; ++j) o[j] = f2bf(acc[j] * 0.0625f);
  *reinterpret_cast<uint4*>(&meanb[(long)bs * DHc + e0]) = *reinterpret_cast<const uint4*>(o);
}

extern "C" void kernel_launch(void* const* d_in, const int* in_sizes, int n_in,
                              void* d_out, int out_size, void* d_ws, size_t ws_size,
                              hipStream_t stream) {
  (void)in_sizes; (void)n_in; (void)out_size; (void)ws_size;
  const float* q  = (const float*)d_in[0];
  const float* k  = (const float*)d_in[1];
  const float* v  = (const float*)d_in[2];
  const float* Wv = (const float*)d_in[4];
  const float* bv = (const float*)d_in[5];
  const float* Wq = (const float*)d_in[6];
  const float* bq = (const float*)d_in[7];
  const float* Wk = (const float*)d_in[8];
  const float* bk = (const float*)d_in[9];
  const float* Wo = (const float*)d_in[10];

  char* ws = (char*)d_ws;
  u16* qbf   = (u16*)(ws + 0);          // 8.0 MB
  u16* kbf   = (u16*)(ws + 8388608);
  u16* vbf   = (u16*)(ws + 16777216);
  u16* Wqbf  = (u16*)(ws + 25165824);   // 2 MB
  u16* Wkbf  = (u16*)(ws + 27262976);
  u16* Wvbf  = (u16*)(ws + 29360128);   // 128 KB (B staging may read into Wobf: defined)
  u16* Wobf  = (u16*)(ws + 29491200);
  u16* qhb   = (u16*)(ws + 29622272);   // 8 MB  [B,H,S,DH]
  u16* khb   = (u16*)(ws + 38010880);
  u16* vTb   = (u16*)(ws + 46399488);   // 512 KB [B,DH,S]
  u16* outh  = (u16*)(ws + 46923776);   // 8 MB  [B,H,S,DH]
  u16* meanb = (u16*)(ws + 55312384);   // 512 KB

  float* outp  = (float*)d_out;
  float* attnp = (float*)d_out + (long)Bc * Sc * Dc;

  auto cvt = [&](const float* in, u16* out, int n) {
    cvt_kernel<<<(n / 4 + 255) / 256, 256, 0, stream>>>(in, out, n / 4);
  };
  cvt(q,  qbf,  Bc * Sc * Dc);
  cvt(k,  kbf,  Bc * Sc * Dc);
  cvt(v,  vbf,  Bc * Sc * Dc);
  cvt(Wq, Wqbf, Hc * DHc * Dc);
  cvt(Wk, Wkbf, Hc * DHc * Dc);
  cvt(Wv, Wvbf, DHc * Dc);
  cvt(Wo, Wobf, Dc * DHc);

  const int M = Bc * Sc;  // 4096
  // qh scale folds 1/sqrt(DH) AND log2(e): attention runs in exp2 domain
  const float qscale = 0.125f * 1.4426950408889634f;
  gemm_bt<<<dim3(8, 32), 256, 0, stream>>>(qbf, Wqbf, bq, M, 1024, 1024, qscale,
      qhb, nullptr, 64, 2097152L, 64L, 131072L, 1L);
  gemm_bt<<<dim3(8, 32), 256, 0, stream>>>(kbf, Wkbf, bk, M, 1024, 1024, 1.0f,
      khb, nullptr, 64, 2097152L, 64L, 131072L, 1L);
  gemm_bt<<<dim3(1, 32), 256, 0, stream>>>(vbf, Wvbf, bv, M, 64, 1024, 1.0f,
      vTb, nullptr, 64, 131072L, 1L, 0L, 2048L);

  attn_fused<<<512, 256, 0, stream>>>(qhb, khb, vTb, outh, attnp);

  mean_kernel<<<128, 256, 0, stream>>>(outh, meanb);

  gemm_bt<<<dim3(8, 32), 256, 0, stream>>>(meanb, Wobf, nullptr, M, 1024, 64, 1.0f,
      nullptr, outp, 1024, 2097152L, 1024L, 0L, 1L);
}

// Round 12
// 286.890 us; speedup vs baseline: 1.4785x; 1.1775x over previous
//
#include <hip/hip_runtime.h>
#include <cstdint>
#include <math.h>

typedef unsigned short u16;
typedef __bf16 bf16x8 __attribute__((ext_vector_type(8)));
typedef float f32x4 __attribute__((ext_vector_type(4)));

constexpr int Bc = 2, Sc = 2048, Dc = 1024, Hc = 16, DHc = 64;

__device__ __forceinline__ u16 f2bf(float f) {
  uint32_t u = __builtin_bit_cast(uint32_t, f);
  u += 0x7fffu + ((u >> 16) & 1u);
  return (u16)(u >> 16);
}
__device__ __forceinline__ float bf2f(u16 h) {
  uint32_t u = ((uint32_t)h) << 16;
  return __builtin_bit_cast(float, u);
}
__device__ __forceinline__ f32x4 mfma16(bf16x8 a, bf16x8 b, f32x4 c) {
  return __builtin_amdgcn_mfma_f32_16x16x32_bf16(a, b, c, 0, 0, 0);
}
// async global->LDS, 16B per lane; LDS base must be wave-uniform, global addr per-lane
__device__ __forceinline__ void gload16(const void* g, void* l) {
  __builtin_amdgcn_global_load_lds((const uint32_t*)g, (uint32_t*)l, 16, 0, 0);
}

// ---------------- single-launch f32 -> bf16 conversion of all 7 tensors ----------------
__global__ __launch_bounds__(256) void cvt_all(
    const float* __restrict__ q, const float* __restrict__ k, const float* __restrict__ v,
    const float* __restrict__ Wq, const float* __restrict__ Wk,
    const float* __restrict__ Wv, const float* __restrict__ Wo,
    u16* __restrict__ qo, u16* __restrict__ ko, u16* __restrict__ vo,
    u16* __restrict__ Wqo, u16* __restrict__ Wko, u16* __restrict__ Wvo,
    u16* __restrict__ Woo) {
  constexpr int NQ = Bc * Sc * Dc / 4;      // 1048576 float4 per q/k/v
  constexpr int NW = Hc * DHc * Dc / 4;     // 262144 per Wq/Wk
  constexpr int NS = DHc * Dc / 4;          // 16384 per Wv/Wo
  constexpr int C1 = NQ, C2 = 2 * NQ, C3 = 3 * NQ;
  constexpr int C4 = C3 + NW, C5 = C4 + NW, C6 = C5 + NS, C7 = C6 + NS;
  const int i = blockIdx.x * 256 + threadIdx.x;
  if (i >= C7) return;
  const float* src; u16* dst; int j;
  if (i < C1)      { src = q;  dst = qo;  j = i; }
  else if (i < C2) { src = k;  dst = ko;  j = i - C1; }
  else if (i < C3) { src = v;  dst = vo;  j = i - C2; }
  else if (i < C4) { src = Wq; dst = Wqo; j = i - C3; }
  else if (i < C5) { src = Wk; dst = Wko; j = i - C4; }
  else if (i < C6) { src = Wv; dst = Wvo; j = i - C5; }
  else             { src = Wo; dst = Woo; j = i - C6; }
  float4 x = reinterpret_cast<const float4*>(src)[j];
  ushort4 o;
  o.x = f2bf(x.x); o.y = f2bf(x.y); o.z = f2bf(x.z); o.w = f2bf(x.w);
  reinterpret_cast<ushort4*>(dst)[j] = o;
}

// ---------------- combined q+k projection GEMM (z picks), M=4096 N=1024 K=1024
// out[b,h,s,e] bf16 at idx = b*2097152 + s*64 + h*131072 + e
__global__ __launch_bounds__(256) void gemm_qk(
    const u16* __restrict__ A0, const u16* __restrict__ A1,
    const u16* __restrict__ B0, const u16* __restrict__ B1,
    const float* __restrict__ bias0, const float* __restrict__ bias1,
    float scale0, float scale1, u16* __restrict__ out0, u16* __restrict__ out1) {
  constexpr int K = 1024;
  const int z = blockIdx.z;
  const u16* A = z ? A1 : A0;
  const u16* Bw = z ? B1 : B0;
  const float* bias = z ? bias1 : bias0;
  const float scale = z ? scale1 : scale0;
  u16* outb = z ? out1 : out0;

  __shared__ u16 As[128 * 32];
  __shared__ u16 Bs[128 * 32];
  const int tid = threadIdx.x;
  const int lane = tid & 63;
  const int w = tid >> 6, wm = w >> 1, wn = w & 1;
  const int lo = lane & 15, hi = lane >> 4;
  const int m0 = blockIdx.y * 128, n0 = blockIdx.x * 128;
  const int r16 = lane >> 2;
  const int c8 = (lane & 3) * 8;
  const f32x4 vzero = {0.f, 0.f, 0.f, 0.f};

  f32x4 acc[4][4];
  #pragma unroll
  for (int i = 0; i < 4; ++i)
    #pragma unroll
    for (int j = 0; j < 4; ++j) acc[i][j] = vzero;

  for (int k0 = 0; k0 < K; k0 += 32) {
    #pragma unroll
    for (int it = 0; it < 2; ++it) {
      const int rg = w * 2 + it;
      const int row = rg * 16 + r16;
      gload16(&A[(long)(m0 + row) * K + k0 + c8], &As[rg * 512]);
      gload16(&Bw[(long)(n0 + row) * K + k0 + c8], &Bs[rg * 512]);
    }
    __syncthreads();
    bf16x8 af[4], bfr[4];
    #pragma unroll
    for (int mi = 0; mi < 4; ++mi)
      af[mi] = *reinterpret_cast<const bf16x8*>(&As[(wm * 64 + mi * 16 + lo) * 32 + hi * 8]);
    #pragma unroll
    for (int nj = 0; nj < 4; ++nj)
      bfr[nj] = *reinterpret_cast<const bf16x8*>(&Bs[(wn * 64 + nj * 16 + lo) * 32 + hi * 8]);
    #pragma unroll
    for (int mi = 0; mi < 4; ++mi)
      #pragma unroll
      for (int nj = 0; nj < 4; ++nj)
        acc[mi][nj] = mfma16(af[mi], bfr[nj], acc[mi][nj]);
    __syncthreads();
  }

  #pragma unroll
  for (int nj = 0; nj < 4; ++nj) {
    const int n = n0 + wn * 64 + nj * 16 + lo;
    const float bb = bias[n];
    const int hh = n >> 6, ee = n & 63;
    #pragma unroll
    for (int mi = 0; mi < 4; ++mi) {
      #pragma unroll
      for (int r = 0; r < 4; ++r) {
        const int mm = m0 + wm * 64 + mi * 16 + hi * 4 + r;
        const int bidx = mm >> 11, ss = mm & 2047;
        const long idx = bidx * 2097152L + ss * 64L + hh * 131072L + ee;
        outb[idx] = f2bf((acc[mi][nj][r] + bb) * scale);
      }
    }
  }
}

// ---------------- generic bf16 GEMM (vproj + final), global_load_lds staging
__global__ __launch_bounds__(256) void gemm_bt(
    const u16* __restrict__ A, const u16* __restrict__ Bw,
    const float* __restrict__ bias, int M, int N, int K, float scale,
    u16* __restrict__ outb, float* __restrict__ outf,
    int DHn, long strideB, long strideS, long strideH, long strideE) {
  __shared__ u16 As[128 * 32];
  __shared__ u16 Bs[128 * 32];
  const int tid = threadIdx.x;
  const int lane = tid & 63;
  const int w = tid >> 6, wm = w >> 1, wn = w & 1;
  const int lo = lane & 15, hi = lane >> 4;
  const int m0 = blockIdx.y * 128, n0 = blockIdx.x * 128;
  const int r16 = lane >> 2;
  const int c8 = (lane & 3) * 8;
  const f32x4 vzero = {0.f, 0.f, 0.f, 0.f};

  f32x4 acc[4][4];
  #pragma unroll
  for (int i = 0; i < 4; ++i)
    #pragma unroll
    for (int j = 0; j < 4; ++j) acc[i][j] = vzero;

  for (int k0 = 0; k0 < K; k0 += 32) {
    #pragma unroll
    for (int it = 0; it < 2; ++it) {
      const int rg = w * 2 + it;
      const int row = rg * 16 + r16;
      gload16(&A[(long)(m0 + row) * K + k0 + c8], &As[rg * 512]);
      gload16(&Bw[(long)(n0 + row) * K + k0 + c8], &Bs[rg * 512]);
    }
    __syncthreads();
    bf16x8 af[4], bfr[4];
    #pragma unroll
    for (int mi = 0; mi < 4; ++mi)
      af[mi] = *reinterpret_cast<const bf16x8*>(&As[(wm * 64 + mi * 16 + lo) * 32 + hi * 8]);
    #pragma unroll
    for (int nj = 0; nj < 4; ++nj)
      bfr[nj] = *reinterpret_cast<const bf16x8*>(&Bs[(wn * 64 + nj * 16 + lo) * 32 + hi * 8]);
    #pragma unroll
    for (int mi = 0; mi < 4; ++mi)
      #pragma unroll
      for (int nj = 0; nj < 4; ++nj)
        acc[mi][nj] = mfma16(af[mi], bfr[nj], acc[mi][nj]);
    __syncthreads();
  }

  #pragma unroll
  for (int nj = 0; nj < 4; ++nj) {
    const int n = n0 + wn * 64 + nj * 16 + lo;
    if (n >= N) continue;
    const float bb = bias ? bias[n] : 0.f;
    const int hh = n / DHn, ee = n % DHn;
    #pragma unroll
    for (int mi = 0; mi < 4; ++mi) {
      #pragma unroll
      for (int r = 0; r < 4; ++r) {
        const int mm = m0 + wm * 64 + mi * 16 + hi * 4 + r;
        const int bidx = mm >> 11, ss = mm & 2047;
        const long idx = bidx * strideB + ss * strideS + hh * strideH + ee * strideE;
        const float val = (acc[mi][nj][r] + bb) * scale;
        if (outf) outf[idx] = val;
        else outb[idx] = f2bf(val);
      }
    }
  }
}

// ---------------- fused causal attention (r11 structure + pass-2 store transpose)
// Fixed-max softmax in exp2 domain (qh pre-scaled by log2(e)/8), M0=16:
//   p' = exp2(z-16) masked, l = sum p', off = 16+log2(l), p = exp2(z-off).
// Pass 1 (mfma(Q,K)): p' + l + LDS-transpose + unnormalized PV.
// Pass 2 (mfma(K,Q), z^T): p -> per-wave f32 LDS transpose -> nt stores of
//   4 rows x 256B contiguous per instruction (was 16 rows x 64B).
__global__ __launch_bounds__(256) void attn_fused(
    const u16* __restrict__ qh, const u16* __restrict__ kh,
    const u16* __restrict__ vT, u16* __restrict__ outh,
    float* __restrict__ attn_out) {
  __shared__ u16 plds[4 * 16 * 80];    // per-wave bf16 P transpose (pass 1)
  __shared__ float pslds[4][16][68];   // per-wave f32 store transpose (pass 2)
  const int tid = threadIdx.x;
  const int lane = tid & 63, w = tid >> 6;
  const int lo = lane & 15, hi = lane >> 4;
  const int blk = blockIdx.x;
  const int sb = blk & 15, h = (blk >> 4) & 15, b = blk >> 8;
  const long bh = (long)(b * Hc + h) * Sc;
  const long rowstride = (long)Hc * Sc;  // 32768
  float* aout = attn_out + (long)b * Sc * rowstride + (long)h * Sc;
  u16* pbuf = &plds[w * 16 * 80];
  float* poff = (float*)pbuf;  // 16 per-row normalizers (read before pass 2)
  float (*pf)[68] = pslds[w];
  const f32x4 vzero = {0.f, 0.f, 0.f, 0.f};
  const int idx = sb * 4 + w;  // 0..63
  const float M0 = 16.f;

  #pragma unroll 1
  for (int sp = 0; sp < 2; ++sp) {
    const int strip = sp ? 127 - idx : idx;
    const int s0 = strip * 16;
    const int smax = s0 + 15;
    const int send = (smax / 64 + 1) * 64;  // live region end, 64-aligned
    const int srow = s0 + hi * 4;           // pass-1 rows
    const int srow2 = s0 + lo;              // pass-2 row

    bf16x8 qa0, qa1;
    {
      const u16* qp = &qh[(bh + s0 + lo) * DHc];
      qa0 = *reinterpret_cast<const bf16x8*>(&qp[hi * 8]);
      qa1 = *reinterpret_cast<const bf16x8*>(&qp[32 + hi * 8]);
    }

    // ---- pass 1: p' = exp2(z-M0), l-sum, LDS transpose, unnormalized PV ----
    float lr[4];
    f32x4 acco[4];
    #pragma unroll
    for (int r = 0; r < 4; ++r) lr[r] = 0.f;
    #pragma unroll
    for (int eb = 0; eb < 4; ++eb) acco[eb] = vzero;

    for (int t0 = 0; t0 < send; t0 += 64) {
      f32x4 z[4];
      #pragma unroll
      for (int c = 0; c < 4; ++c) {
        const u16* kp = &kh[(bh + t0 + c * 16 + lo) * DHc];
        bf16x8 kb0 = *reinterpret_cast<const bf16x8*>(&kp[hi * 8]);
        bf16x8 kb1 = *reinterpret_cast<const bf16x8*>(&kp[32 + hi * 8]);
        f32x4 zz = mfma16(qa0, kb0, vzero);
        z[c] = mfma16(qa1, kb1, zz);
      }
      const bool full = (t0 + 63 <= s0);
      #pragma unroll
      for (int r = 0; r < 4; ++r) {
        const int s = srow + r;
        #pragma unroll
        for (int c = 0; c < 4; ++c) {
          float e = exp2f(z[c][r] - M0);
          if (!full) e = ((t0 + c * 16 + lo) <= s) ? e : 0.f;
          lr[r] += e;
          pbuf[(hi * 4 + r) * 80 + c * 16 + lo] = f2bf(e);
        }
      }
      asm volatile("s_waitcnt lgkmcnt(0)" ::: "memory");
      __builtin_amdgcn_sched_barrier(0);
      bf16x8 pa0 = *reinterpret_cast<const bf16x8*>(&pbuf[lo * 80 + hi * 8]);
      bf16x8 pa1 = *reinterpret_cast<const bf16x8*>(&pbuf[lo * 80 + 32 + hi * 8]);
      const u16* vp = &vT[((long)b * DHc + lo) * Sc + t0 + hi * 8];
      #pragma unroll
      for (int eb = 0; eb < 4; ++eb) {
        bf16x8 vb0 = *reinterpret_cast<const bf16x8*>(&vp[(long)eb * 16 * Sc]);
        bf16x8 vb1 = *reinterpret_cast<const bf16x8*>(&vp[(long)eb * 16 * Sc + 32]);
        acco[eb] = mfma16(pa0, vb0, acco[eb]);
        acco[eb] = mfma16(pa1, vb1, acco[eb]);
      }
    }
    // sum l across the 16 column-lanes (pure adds: fixed max)
    float inv[4];
    #pragma unroll
    for (int r = 0; r < 4; ++r) {
      #pragma unroll
      for (int dd = 1; dd < 16; dd <<= 1) lr[r] += __shfl_xor(lr[r], dd);
      inv[r] = 1.f / lr[r];
    }
    // publish per-row off = M0 + log2(l) for pass 2
    if (lo == 0) {
      #pragma unroll
      for (int r = 0; r < 4; ++r) poff[hi * 4 + r] = M0 + __log2f(lr[r]);
    }
    asm volatile("s_waitcnt lgkmcnt(0)" ::: "memory");
    __builtin_amdgcn_sched_barrier(0);
    const float offv = poff[lo];

    // ---- pass 2: z^T recompute, p = exp2(z-off), transposed 256B-segment stores ----
    const int r4 = lane >> 4;          // store row-within-quad
    const int c4 = (lane & 15) * 4;    // store col
    for (int t0 = 0; t0 < send; t0 += 64) {
      const bool full = (t0 + 63 <= s0);
      #pragma unroll
      for (int c = 0; c < 4; ++c) {
        const u16* kp = &kh[(bh + t0 + c * 16 + lo) * DHc];
        bf16x8 kb0 = *reinterpret_cast<const bf16x8*>(&kp[hi * 8]);
        bf16x8 kb1 = *reinterpret_cast<const bf16x8*>(&kp[32 + hi * 8]);
        f32x4 zt = mfma16(kb1, qa1, mfma16(kb0, qa0, vzero));
        f32x4 p;
        #pragma unroll
        for (int r = 0; r < 4; ++r) {
          const float e = exp2f(zt[r] - offv);
          p[r] = (full || (t0 + c * 16 + hi * 4 + r <= srow2)) ? e : 0.f;
        }
        *reinterpret_cast<f32x4*>(&pf[lo][c * 16 + hi * 4]) = p;
      }
      asm volatile("s_waitcnt lgkmcnt(0)" ::: "memory");
      __builtin_amdgcn_sched_barrier(0);
      #pragma unroll
      for (int j = 0; j < 4; ++j) {
        f32x4 v = *reinterpret_cast<const f32x4*>(&pf[j * 4 + r4][c4]);
        __builtin_nontemporal_store(
            v, reinterpret_cast<f32x4*>(aout + (long)(s0 + j * 4 + r4) * rowstride + t0 + c4));
      }
    }

    // ---- epilogue: outh store (scaled by 1/l) + nt zero-fill masked region ----
    #pragma unroll
    for (int eb = 0; eb < 4; ++eb)
      #pragma unroll
      for (int r = 0; r < 4; ++r)
        outh[(bh + srow + r) * DHc + eb * 16 + lo] = f2bf(acco[eb][r] * inv[r]);

    const f32x4 z4 = {0.f, 0.f, 0.f, 0.f};
    for (int t0 = send; t0 < Sc; t0 += 64) {
      #pragma unroll
      for (int r = 0; r < 4; ++r)
        __builtin_nontemporal_store(
            z4, reinterpret_cast<f32x4*>(aout + (long)(srow + r) * rowstride + t0 + lo * 4));
    }
  }
}

// ---------------- mean over heads
__global__ __launch_bounds__(256) void mean_kernel(const u16* __restrict__ outh,
                                                   u16* __restrict__ meanb) {
  const int idx = blockIdx.x * 256 + threadIdx.x;  // 32768 threads
  const int bs = idx >> 3;
  const int e0 = (idx & 7) * 8;
  const int b = bs >> 11, s = bs & 2047;
  float acc[8];
  #pragma unroll
  for (int j = 0; j < 8; ++j) acc[j] = 0.f;
  for (int h = 0; h < Hc; ++h) {
    alignas(16) u16 tmp[8];
    *reinterpret_cast<uint4*>(tmp) =
        *reinterpret_cast<const uint4*>(&outh[((long)(b * Hc + h) * Sc + s) * DHc + e0]);
    #pragma unroll
    for (int j = 0; j < 8; ++j) acc[j] += bf2f(tmp[j]);
  }
  alignas(16) u16 o[8];
  #pragma unroll
  for (int j = 0; j < 8; ++j) o[j] = f2bf(acc[j] * 0.0625f);
  *reinterpret_cast<uint4*>(&meanb[(long)bs * DHc + e0]) = *reinterpret_cast<const uint4*>(o);
}

extern "C" void kernel_launch(void* const* d_in, const int* in_sizes, int n_in,
                              void* d_out, int out_size, void* d_ws, size_t ws_size,
                              hipStream_t stream) {
  (void)in_sizes; (void)n_in; (void)out_size; (void)ws_size;
  const float* q  = (const float*)d_in[0];
  const float* k  = (const float*)d_in[1];
  const float* v  = (const float*)d_in[2];
  const float* Wv = (const float*)d_in[4];
  const float* bv = (const float*)d_in[5];
  const float* Wq = (const float*)d_in[6];
  const float* bq = (const float*)d_in[7];
  const float* Wk = (const float*)d_in[8];
  const float* bk = (const float*)d_in[9];
  const float* Wo = (const float*)d_in[10];

  char* ws = (char*)d_ws;
  u16* qbf   = (u16*)(ws + 0);          // 8.0 MB
  u16* kbf   = (u16*)(ws + 8388608);
  u16* vbf   = (u16*)(ws + 16777216);
  u16* Wqbf  = (u16*)(ws + 25165824);   // 2 MB
  u16* Wkbf  = (u16*)(ws + 27262976);
  u16* Wvbf  = (u16*)(ws + 29360128);   // 128 KB (B staging may read into Wobf: defined)
  u16* Wobf  = (u16*)(ws + 29491200);
  u16* qhb   = (u16*)(ws + 29622272);   // 8 MB  [B,H,S,DH]
  u16* khb   = (u16*)(ws + 38010880);
  u16* vTb   = (u16*)(ws + 46399488);   // 512 KB [B,DH,S]
  u16* outh  = (u16*)(ws + 46923776);   // 8 MB  [B,H,S,DH]
  u16* meanb = (u16*)(ws + 55312384);   // 512 KB

  float* outp  = (float*)d_out;
  float* attnp = (float*)d_out + (long)Bc * Sc * Dc;

  // one launch: all f32 -> bf16 conversions (3.7M float4)
  cvt_all<<<(3702784 + 255) / 256, 256, 0, stream>>>(
      q, k, v, Wq, Wk, Wv, Wo, qbf, kbf, vbf, Wqbf, Wkbf, Wvbf, Wobf);

  const int M = Bc * Sc;  // 4096
  // qh scale folds 1/sqrt(DH) AND log2(e): attention runs in exp2 domain
  const float qscale = 0.125f * 1.4426950408889634f;
  gemm_qk<<<dim3(8, 32, 2), 256, 0, stream>>>(
      qbf, kbf, Wqbf, Wkbf, bq, bk, qscale, 1.0f, qhb, khb);
  gemm_bt<<<dim3(1, 32), 256, 0, stream>>>(vbf, Wvbf, bv, M, 64, 1024, 1.0f,
      vTb, nullptr, 64, 131072L, 1L, 0L, 2048L);

  attn_fused<<<512, 256, 0, stream>>>(qhb, khb, vTb, outh, attnp);

  mean_kernel<<<128, 256, 0, stream>>>(outh, meanb);

  gemm_bt<<<dim3(8, 32), 256, 0, stream>>>(meanb, Wobf, nullptr, M, 1024, 64, 1.0f,
      nullptr, outp, 1024, 2097152L, 1024L, 0L, 1L);
}

// Round 13
// 267.379 us; speedup vs baseline: 1.5864x; 1.0730x over previous
//
#include <hip/hip_runtime.h>
#include <cstdint>
#include <math.h>

typedef unsigned short u16;
typedef __bf16 bf16x8 __attribute__((ext_vector_type(8)));
typedef float f32x4 __attribute__((ext_vector_type(4)));

constexpr int Bc = 2, Sc = 2048, Dc = 1024, Hc = 16, DHc = 64;

__device__ __forceinline__ u16 f2bf(float f) {
  uint32_t u = __builtin_bit_cast(uint32_t, f);
  u += 0x7fffu + ((u >> 16) & 1u);
  return (u16)(u >> 16);
}
__device__ __forceinline__ float bf2f(u16 h) {
  uint32_t u = ((uint32_t)h) << 16;
  return __builtin_bit_cast(float, u);
}
__device__ __forceinline__ f32x4 mfma16(bf16x8 a, bf16x8 b, f32x4 c) {
  return __builtin_amdgcn_mfma_f32_16x16x32_bf16(a, b, c, 0, 0, 0);
}
// async global->LDS, 16B per lane; LDS base must be wave-uniform, global addr per-lane
__device__ __forceinline__ void gload16(const void* g, void* l) {
  __builtin_amdgcn_global_load_lds((const uint32_t*)g, (uint32_t*)l, 16, 0, 0);
}
// two f32x4 -> bf16x8 (RNE)
__device__ __forceinline__ bf16x8 pk8(f32x4 a, f32x4 b) {
  alignas(16) u16 t[8];
  #pragma unroll
  for (int j = 0; j < 4; ++j) { t[j] = f2bf(a[j]); t[4 + j] = f2bf(b[j]); }
  return *reinterpret_cast<const bf16x8*>(t);
}

// ---------------- single-launch f32 -> bf16 conversion of all 7 tensors ----------------
__global__ __launch_bounds__(256) void cvt_all(
    const float* __restrict__ q, const float* __restrict__ k, const float* __restrict__ v,
    const float* __restrict__ Wq, const float* __restrict__ Wk,
    const float* __restrict__ Wv, const float* __restrict__ Wo,
    u16* __restrict__ qo, u16* __restrict__ ko, u16* __restrict__ vo,
    u16* __restrict__ Wqo, u16* __restrict__ Wko, u16* __restrict__ Wvo,
    u16* __restrict__ Woo) {
  constexpr int NQ = Bc * Sc * Dc / 4;      // 1048576 float4 per q/k/v
  constexpr int NW = Hc * DHc * Dc / 4;     // 262144 per Wq/Wk
  constexpr int NS = DHc * Dc / 4;          // 16384 per Wv/Wo
  constexpr int C1 = NQ, C2 = 2 * NQ, C3 = 3 * NQ;
  constexpr int C4 = C3 + NW, C5 = C4 + NW, C6 = C5 + NS, C7 = C6 + NS;
  const int i = blockIdx.x * 256 + threadIdx.x;
  if (i >= C7) return;
  const float* src; u16* dst; int j;
  if (i < C1)      { src = q;  dst = qo;  j = i; }
  else if (i < C2) { src = k;  dst = ko;  j = i - C1; }
  else if (i < C3) { src = v;  dst = vo;  j = i - C2; }
  else if (i < C4) { src = Wq; dst = Wqo; j = i - C3; }
  else if (i < C5) { src = Wk; dst = Wko; j = i - C4; }
  else if (i < C6) { src = Wv; dst = Wvo; j = i - C5; }
  else             { src = Wo; dst = Woo; j = i - C6; }
  float4 x = reinterpret_cast<const float4*>(src)[j];
  ushort4 o;
  o.x = f2bf(x.x); o.y = f2bf(x.y); o.z = f2bf(x.z); o.w = f2bf(x.w);
  reinterpret_cast<ushort4*>(dst)[j] = o;
}

// ---------------- combined q+k+v projection GEMM; z selects operand set.
// z=0: qh (scale=qscale), z=1: kh, both [B,H,S,DH]-strided bf16.
// z=2 (blockIdx.x==0 only): vT [B,DH,S] bf16, N=64 (over-read rows discarded).
__global__ __launch_bounds__(256) void gemm_qkv(
    const u16* __restrict__ qbf, const u16* __restrict__ kbf, const u16* __restrict__ vbf,
    const u16* __restrict__ Wqb, const u16* __restrict__ Wkb, const u16* __restrict__ Wvb,
    const float* __restrict__ bq, const float* __restrict__ bk, const float* __restrict__ bv,
    float qscale, u16* __restrict__ qh, u16* __restrict__ kh, u16* __restrict__ vT) {
  constexpr int K = 1024;
  const int z = blockIdx.z;
  if (z == 2 && blockIdx.x != 0) return;
  const u16* A  = z == 0 ? qbf : (z == 1 ? kbf : vbf);
  const u16* Bw = z == 0 ? Wqb : (z == 1 ? Wkb : Wvb);
  const float* bias = z == 0 ? bq : (z == 1 ? bk : bv);
  const float scale = z == 0 ? qscale : 1.0f;

  __shared__ u16 As[128 * 32];
  __shared__ u16 Bs[128 * 32];
  const int tid = threadIdx.x;
  const int lane = tid & 63;
  const int w = tid >> 6, wm = w >> 1, wn = w & 1;
  const int lo = lane & 15, hi = lane >> 4;
  const int m0 = blockIdx.y * 128, n0 = blockIdx.x * 128;
  const int r16 = lane >> 2;
  const int c8 = (lane & 3) * 8;
  const f32x4 vzero = {0.f, 0.f, 0.f, 0.f};

  f32x4 acc[4][4];
  #pragma unroll
  for (int i = 0; i < 4; ++i)
    #pragma unroll
    for (int j = 0; j < 4; ++j) acc[i][j] = vzero;

  for (int k0 = 0; k0 < K; k0 += 32) {
    #pragma unroll
    for (int it = 0; it < 2; ++it) {
      const int rg = w * 2 + it;
      const int row = rg * 16 + r16;
      gload16(&A[(long)(m0 + row) * K + k0 + c8], &As[rg * 512]);
      gload16(&Bw[(long)(n0 + row) * K + k0 + c8], &Bs[rg * 512]);
    }
    __syncthreads();
    bf16x8 af[4], bfr[4];
    #pragma unroll
    for (int mi = 0; mi < 4; ++mi)
      af[mi] = *reinterpret_cast<const bf16x8*>(&As[(wm * 64 + mi * 16 + lo) * 32 + hi * 8]);
    #pragma unroll
    for (int nj = 0; nj < 4; ++nj)
      bfr[nj] = *reinterpret_cast<const bf16x8*>(&Bs[(wn * 64 + nj * 16 + lo) * 32 + hi * 8]);
    #pragma unroll
    for (int mi = 0; mi < 4; ++mi)
      #pragma unroll
      for (int nj = 0; nj < 4; ++nj)
        acc[mi][nj] = mfma16(af[mi], bfr[nj], acc[mi][nj]);
    __syncthreads();
  }

  #pragma unroll
  for (int nj = 0; nj < 4; ++nj) {
    const int n = n0 + wn * 64 + nj * 16 + lo;
    if (z == 2 && n >= 64) continue;
    const float bb = bias[n];
    #pragma unroll
    for (int mi = 0; mi < 4; ++mi) {
      #pragma unroll
      for (int r = 0; r < 4; ++r) {
        const int mm = m0 + wm * 64 + mi * 16 + hi * 4 + r;
        const int bidx = mm >> 11, ss = mm & 2047;
        const float val = (acc[mi][nj][r] + bb) * scale;
        if (z < 2) {
          const int hh = n >> 6, ee = n & 63;
          const long idx = bidx * 2097152L + ss * 64L + hh * 131072L + ee;
          (z ? kh : qh)[idx] = f2bf(val);
        } else {
          vT[bidx * 131072L + n * 2048L + ss] = f2bf(val);
        }
      }
    }
  }
}

// ---------------- generic bf16 GEMM (final proj), global_load_lds staging
__global__ __launch_bounds__(256) void gemm_bt(
    const u16* __restrict__ A, const u16* __restrict__ Bw,
    const float* __restrict__ bias, int M, int N, int K, float scale,
    u16* __restrict__ outb, float* __restrict__ outf,
    int DHn, long strideB, long strideS, long strideH, long strideE) {
  __shared__ u16 As[128 * 32];
  __shared__ u16 Bs[128 * 32];
  const int tid = threadIdx.x;
  const int lane = tid & 63;
  const int w = tid >> 6, wm = w >> 1, wn = w & 1;
  const int lo = lane & 15, hi = lane >> 4;
  const int m0 = blockIdx.y * 128, n0 = blockIdx.x * 128;
  const int r16 = lane >> 2;
  const int c8 = (lane & 3) * 8;
  const f32x4 vzero = {0.f, 0.f, 0.f, 0.f};

  f32x4 acc[4][4];
  #pragma unroll
  for (int i = 0; i < 4; ++i)
    #pragma unroll
    for (int j = 0; j < 4; ++j) acc[i][j] = vzero;

  for (int k0 = 0; k0 < K; k0 += 32) {
    #pragma unroll
    for (int it = 0; it < 2; ++it) {
      const int rg = w * 2 + it;
      const int row = rg * 16 + r16;
      gload16(&A[(long)(m0 + row) * K + k0 + c8], &As[rg * 512]);
      gload16(&Bw[(long)(n0 + row) * K + k0 + c8], &Bs[rg * 512]);
    }
    __syncthreads();
    bf16x8 af[4], bfr[4];
    #pragma unroll
    for (int mi = 0; mi < 4; ++mi)
      af[mi] = *reinterpret_cast<const bf16x8*>(&As[(wm * 64 + mi * 16 + lo) * 32 + hi * 8]);
    #pragma unroll
    for (int nj = 0; nj < 4; ++nj)
      bfr[nj] = *reinterpret_cast<const bf16x8*>(&Bs[(wn * 64 + nj * 16 + lo) * 32 + hi * 8]);
    #pragma unroll
    for (int mi = 0; mi < 4; ++mi)
      #pragma unroll
      for (int nj = 0; nj < 4; ++nj)
        acc[mi][nj] = mfma16(af[mi], bfr[nj], acc[mi][nj]);
    __syncthreads();
  }

  #pragma unroll
  for (int nj = 0; nj < 4; ++nj) {
    const int n = n0 + wn * 64 + nj * 16 + lo;
    if (n >= N) continue;
    const float bb = bias ? bias[n] : 0.f;
    const int hh = n / DHn, ee = n % DHn;
    #pragma unroll
    for (int mi = 0; mi < 4; ++mi) {
      #pragma unroll
      for (int r = 0; r < 4; ++r) {
        const int mm = m0 + wm * 64 + mi * 16 + hi * 4 + r;
        const int bidx = mm >> 11, ss = mm & 2047;
        const long idx = bidx * strideB + ss * strideS + hh * strideH + ee * strideE;
        const float val = (acc[mi][nj][r] + bb) * scale;
        if (outf) outf[idx] = val;
        else outb[idx] = f2bf(val);
      }
    }
  }
}

// ---------------- fused causal attention (r12 + PV moved to pass 2)
// Fixed-max softmax in exp2 domain (qh pre-scaled by log2(e)/8), M0=16:
//   l = sum exp2(z-M0) masked, off = 16+log2(l), p = exp2(z-off) (normalized).
// Pass 1 (mfma(Q,K)): exp + l-sum only (no LDS).
// Pass 2 (mfma(K,Q), z^T): p -> pslds f32 transpose -> 256B-segment nt stores
//   AND PV A-fragments read back from pslds (normalized p -> outh directly).
__global__ __launch_bounds__(256) void attn_fused(
    const u16* __restrict__ qh, const u16* __restrict__ kh,
    const u16* __restrict__ vT, u16* __restrict__ outh,
    float* __restrict__ attn_out) {
  __shared__ float pslds[4][16][68];   // per-wave f32 P transpose (pass 2)
  __shared__ float pofflds[4][16];     // per-wave per-row normalizer
  const int tid = threadIdx.x;
  const int lane = tid & 63, w = tid >> 6;
  const int lo = lane & 15, hi = lane >> 4;
  const int blk = blockIdx.x;
  const int sb = blk & 15, h = (blk >> 4) & 15, b = blk >> 8;
  const long bh = (long)(b * Hc + h) * Sc;
  const long rowstride = (long)Hc * Sc;  // 32768
  float* aout = attn_out + (long)b * Sc * rowstride + (long)h * Sc;
  float (*pf)[68] = pslds[w];
  float* poff = pofflds[w];
  const f32x4 vzero = {0.f, 0.f, 0.f, 0.f};
  const int idx = sb * 4 + w;  // 0..63
  const float M0 = 16.f;

  #pragma unroll 1
  for (int sp = 0; sp < 2; ++sp) {
    const int strip = sp ? 127 - idx : idx;
    const int s0 = strip * 16;
    const int smax = s0 + 15;
    const int send = (smax / 64 + 1) * 64;  // live region end, 64-aligned
    const int srow = s0 + hi * 4;           // pass-1 rows
    const int srow2 = s0 + lo;              // pass-2 row

    bf16x8 qa0, qa1;
    {
      const u16* qp = &qh[(bh + s0 + lo) * DHc];
      qa0 = *reinterpret_cast<const bf16x8*>(&qp[hi * 8]);
      qa1 = *reinterpret_cast<const bf16x8*>(&qp[32 + hi * 8]);
    }

    // ---- pass 1: l = sum exp2(z-M0) over causal range (no LDS, no PV) ----
    float lr[4];
    #pragma unroll
    for (int r = 0; r < 4; ++r) lr[r] = 0.f;

    for (int t0 = 0; t0 < send; t0 += 64) {
      f32x4 z[4];
      #pragma unroll
      for (int c = 0; c < 4; ++c) {
        const u16* kp = &kh[(bh + t0 + c * 16 + lo) * DHc];
        bf16x8 kb0 = *reinterpret_cast<const bf16x8*>(&kp[hi * 8]);
        bf16x8 kb1 = *reinterpret_cast<const bf16x8*>(&kp[32 + hi * 8]);
        f32x4 zz = mfma16(qa0, kb0, vzero);
        z[c] = mfma16(qa1, kb1, zz);
      }
      const bool full = (t0 + 63 <= s0);
      #pragma unroll
      for (int r = 0; r < 4; ++r) {
        const int s = srow + r;
        #pragma unroll
        for (int c = 0; c < 4; ++c) {
          float e = exp2f(z[c][r] - M0);
          if (!full) e = ((t0 + c * 16 + lo) <= s) ? e : 0.f;
          lr[r] += e;
        }
      }
    }
    // sum l across the 16 column-lanes, publish off = M0 + log2(l)
    #pragma unroll
    for (int r = 0; r < 4; ++r) {
      #pragma unroll
      for (int dd = 1; dd < 16; dd <<= 1) lr[r] += __shfl_xor(lr[r], dd);
    }
    if (lo == 0) {
      #pragma unroll
      for (int r = 0; r < 4; ++r) poff[hi * 4 + r] = M0 + __log2f(lr[r]);
    }
    asm volatile("s_waitcnt lgkmcnt(0)" ::: "memory");
    __builtin_amdgcn_sched_barrier(0);
    const float offv = poff[lo];

    // ---- pass 2: z^T recompute, p=exp2(z-off) -> LDS -> 256B nt stores + PV ----
    f32x4 acco[4];
    #pragma unroll
    for (int eb = 0; eb < 4; ++eb) acco[eb] = vzero;
    const int r4 = lane >> 4;          // store row-within-quad
    const int c4 = (lane & 15) * 4;    // store col
    for (int t0 = 0; t0 < send; t0 += 64) {
      const bool full = (t0 + 63 <= s0);
      #pragma unroll
      for (int c = 0; c < 4; ++c) {
        const u16* kp = &kh[(bh + t0 + c * 16 + lo) * DHc];
        bf16x8 kb0 = *reinterpret_cast<const bf16x8*>(&kp[hi * 8]);
        bf16x8 kb1 = *reinterpret_cast<const bf16x8*>(&kp[32 + hi * 8]);
        f32x4 zt = mfma16(kb1, qa1, mfma16(kb0, qa0, vzero));
        f32x4 p;
        #pragma unroll
        for (int r = 0; r < 4; ++r) {
          const float e = exp2f(zt[r] - offv);
          p[r] = (full || (t0 + c * 16 + hi * 4 + r <= srow2)) ? e : 0.f;
        }
        *reinterpret_cast<f32x4*>(&pf[lo][c * 16 + hi * 4]) = p;
      }
      asm volatile("s_waitcnt lgkmcnt(0)" ::: "memory");
      __builtin_amdgcn_sched_barrier(0);
      // transposed nontemporal stores: 4 rows x 256B contiguous
      #pragma unroll
      for (int j = 0; j < 4; ++j) {
        f32x4 v = *reinterpret_cast<const f32x4*>(&pf[j * 4 + r4][c4]);
        __builtin_nontemporal_store(
            v, reinterpret_cast<f32x4*>(aout + (long)(s0 + j * 4 + r4) * rowstride + t0 + c4));
      }
      // PV: A-fragment (row lo, k = hi*8.. / 32+hi*8..) from pslds, normalized p
      f32x4 a0 = *reinterpret_cast<const f32x4*>(&pf[lo][hi * 8]);
      f32x4 a1 = *reinterpret_cast<const f32x4*>(&pf[lo][hi * 8 + 4]);
      f32x4 a2 = *reinterpret_cast<const f32x4*>(&pf[lo][32 + hi * 8]);
      f32x4 a3 = *reinterpret_cast<const f32x4*>(&pf[lo][32 + hi * 8 + 4]);
      bf16x8 pa0 = pk8(a0, a1);
      bf16x8 pa1 = pk8(a2, a3);
      const u16* vp = &vT[((long)b * DHc + lo) * Sc + t0 + hi * 8];
      #pragma unroll
      for (int eb = 0; eb < 4; ++eb) {
        bf16x8 vb0 = *reinterpret_cast<const bf16x8*>(&vp[(long)eb * 16 * Sc]);
        bf16x8 vb1 = *reinterpret_cast<const bf16x8*>(&vp[(long)eb * 16 * Sc + 32]);
        acco[eb] = mfma16(pa0, vb0, acco[eb]);
        acco[eb] = mfma16(pa1, vb1, acco[eb]);
      }
    }

    // ---- epilogue: outh store (already normalized) + nt zero-fill masked region ----
    #pragma unroll
    for (int eb = 0; eb < 4; ++eb)
      #pragma unroll
      for (int r = 0; r < 4; ++r)
        outh[(bh + srow + r) * DHc + eb * 16 + lo] = f2bf(acco[eb][r]);

    const f32x4 z4 = {0.f, 0.f, 0.f, 0.f};
    for (int t0 = send; t0 < Sc; t0 += 64) {
      #pragma unroll
      for (int r = 0; r < 4; ++r)
        __builtin_nontemporal_store(
            z4, reinterpret_cast<f32x4*>(aout + (long)(srow + r) * rowstride + t0 + lo * 4));
    }
  }
}

// ---------------- mean over heads
__global__ __launch_bounds__(256) void mean_kernel(const u16* __restrict__ outh,
                                                   u16* __restrict__ meanb) {
  const int idx = blockIdx.x * 256 + threadIdx.x;  // 32768 threads
  const int bs = idx >> 3;
  const int e0 = (idx & 7) * 8;
  const int b = bs >> 11, s = bs & 2047;
  float acc[8];
  #pragma unroll
  for (int j = 0; j < 8; ++j) acc[j] = 0.f;
  for (int h = 0; h < Hc; ++h) {
    alignas(16) u16 tmp[8];
    *reinterpret_cast<uint4*>(tmp) =
        *reinterpret_cast<const uint4*>(&outh[((long)(b * Hc + h) * Sc + s) * DHc + e0]);
    #pragma unroll
    for (int j = 0; j < 8; ++j) acc[j] += bf2f(tmp[j]);
  }
  alignas(16) u16 o[8];
  #pragma unroll
  for (int j = 0; j < 8; ++j) o[j] = f2bf(acc[j] * 0.0625f);
  *reinterpret_cast<uint4*>(&meanb[(long)bs * DHc + e0]) = *reinterpret_cast<const uint4*>(o);
}

extern "C" void kernel_launch(void* const* d_in, const int* in_sizes, int n_in,
                              void* d_out, int out_size, void* d_ws, size_t ws_size,
                              hipStream_t stream) {
  (void)in_sizes; (void)n_in; (void)out_size; (void)ws_size;
  const float* q  = (const float*)d_in[0];
  const float* k  = (const float*)d_in[1];
  const float* v  = (const float*)d_in[2];
  const float* Wv = (const float*)d_in[4];
  const float* bv = (const float*)d_in[5];
  const float* Wq = (const float*)d_in[6];
  const float* bq = (const float*)d_in[7];
  const float* Wk = (const float*)d_in[8];
  const float* bk = (const float*)d_in[9];
  const float* Wo = (const float*)d_in[10];

  char* ws = (char*)d_ws;
  u16* qbf   = (u16*)(ws + 0);          // 8.0 MB
  u16* kbf   = (u16*)(ws + 8388608);
  u16* vbf   = (u16*)(ws + 16777216);
  u16* Wqbf  = (u16*)(ws + 25165824);   // 2 MB
  u16* Wkbf  = (u16*)(ws + 27262976);
  u16* Wvbf  = (u16*)(ws + 29360128);   // 128 KB (B staging may read into Wobf: defined)
  u16* Wobf  = (u16*)(ws + 29491200);
  u16* qhb   = (u16*)(ws + 29622272);   // 8 MB  [B,H,S,DH]
  u16* khb   = (u16*)(ws + 38010880);
  u16* vTb   = (u16*)(ws + 46399488);   // 512 KB [B,DH,S]
  u16* outh  = (u16*)(ws + 46923776);   // 8 MB  [B,H,S,DH]
  u16* meanb = (u16*)(ws + 55312384);   // 512 KB

  float* outp  = (float*)d_out;
  float* attnp = (float*)d_out + (long)Bc * Sc * Dc;

  // one launch: all f32 -> bf16 conversions (3.7M float4)
  cvt_all<<<(3702784 + 255) / 256, 256, 0, stream>>>(
      q, k, v, Wq, Wk, Wv, Wo, qbf, kbf, vbf, Wqbf, Wkbf, Wvbf, Wobf);

  const int M = Bc * Sc;  // 4096
  // qh scale folds 1/sqrt(DH) AND log2(e): attention runs in exp2 domain
  const float qscale = 0.125f * 1.4426950408889634f;
  gemm_qkv<<<dim3(8, 32, 3), 256, 0, stream>>>(
      qbf, kbf, vbf, Wqbf, Wkbf, Wvbf, bq, bk, bv, qscale, qhb, khb, vTb);

  attn_fused<<<512, 256, 0, stream>>>(qhb, khb, vTb, outh, attnp);

  mean_kernel<<<128, 256, 0, stream>>>(outh, meanb);

  gemm_bt<<<dim3(8, 32), 256, 0, stream>>>(meanb, Wobf, nullptr, M, 1024, 64, 1.0f,
      nullptr, outp, 1024, 2097152L, 1024L, 0L, 1L);
}

// Round 14
// 255.777 us; speedup vs baseline: 1.6584x; 1.0454x over previous
//
#include <hip/hip_runtime.h>
#include <cstdint>
#include <math.h>

typedef unsigned short u16;
typedef __bf16 bf16x8 __attribute__((ext_vector_type(8)));
typedef float f32x4 __attribute__((ext_vector_type(4)));

constexpr int Bc = 2, Sc = 2048, Dc = 1024, Hc = 16, DHc = 64;

__device__ __forceinline__ u16 f2bf(float f) {
  uint32_t u = __builtin_bit_cast(uint32_t, f);
  u += 0x7fffu + ((u >> 16) & 1u);
  return (u16)(u >> 16);
}
__device__ __forceinline__ float bf2f(u16 h) {
  uint32_t u = ((uint32_t)h) << 16;
  return __builtin_bit_cast(float, u);
}
__device__ __forceinline__ f32x4 mfma16(bf16x8 a, bf16x8 b, f32x4 c) {
  return __builtin_amdgcn_mfma_f32_16x16x32_bf16(a, b, c, 0, 0, 0);
}
// async global->LDS, 16B per lane; LDS base must be wave-uniform, global addr per-lane
__device__ __forceinline__ void gload16(const void* g, void* l) {
  __builtin_amdgcn_global_load_lds((const uint32_t*)g, (uint32_t*)l, 16, 0, 0);
}
// two f32x4 -> bf16x8 (RNE)
__device__ __forceinline__ bf16x8 pk8(f32x4 a, f32x4 b) {
  alignas(16) u16 t[8];
  #pragma unroll
  for (int j = 0; j < 4; ++j) { t[j] = f2bf(a[j]); t[4 + j] = f2bf(b[j]); }
  return *reinterpret_cast<const bf16x8*>(t);
}

// ---------------- single-launch f32 -> bf16 conversion of all 7 tensors ----------------
__global__ __launch_bounds__(256) void cvt_all(
    const float* __restrict__ q, const float* __restrict__ k, const float* __restrict__ v,
    const float* __restrict__ Wq, const float* __restrict__ Wk,
    const float* __restrict__ Wv, const float* __restrict__ Wo,
    u16* __restrict__ qo, u16* __restrict__ ko, u16* __restrict__ vo,
    u16* __restrict__ Wqo, u16* __restrict__ Wko, u16* __restrict__ Wvo,
    u16* __restrict__ Woo) {
  constexpr int NQ = Bc * Sc * Dc / 4;      // 1048576 float4 per q/k/v
  constexpr int NW = Hc * DHc * Dc / 4;     // 262144 per Wq/Wk
  constexpr int NS = DHc * Dc / 4;          // 16384 per Wv/Wo
  constexpr int C1 = NQ, C2 = 2 * NQ, C3 = 3 * NQ;
  constexpr int C4 = C3 + NW, C5 = C4 + NW, C6 = C5 + NS, C7 = C6 + NS;
  const int i = blockIdx.x * 256 + threadIdx.x;
  if (i >= C7) return;
  const float* src; u16* dst; int j;
  if (i < C1)      { src = q;  dst = qo;  j = i; }
  else if (i < C2) { src = k;  dst = ko;  j = i - C1; }
  else if (i < C3) { src = v;  dst = vo;  j = i - C2; }
  else if (i < C4) { src = Wq; dst = Wqo; j = i - C3; }
  else if (i < C5) { src = Wk; dst = Wko; j = i - C4; }
  else if (i < C6) { src = Wv; dst = Wvo; j = i - C5; }
  else             { src = Wo; dst = Woo; j = i - C6; }
  float4 x = reinterpret_cast<const float4*>(src)[j];
  ushort4 o;
  o.x = f2bf(x.x); o.y = f2bf(x.y); o.z = f2bf(x.z); o.w = f2bf(x.w);
  reinterpret_cast<ushort4*>(dst)[j] = o;
}

// ---------------- combined q+k+v projection GEMM; z selects operand set.
__global__ __launch_bounds__(256) void gemm_qkv(
    const u16* __restrict__ qbf, const u16* __restrict__ kbf, const u16* __restrict__ vbf,
    const u16* __restrict__ Wqb, const u16* __restrict__ Wkb, const u16* __restrict__ Wvb,
    const float* __restrict__ bq, const float* __restrict__ bk, const float* __restrict__ bv,
    float qscale, u16* __restrict__ qh, u16* __restrict__ kh, u16* __restrict__ vT) {
  constexpr int K = 1024;
  const int z = blockIdx.z;
  if (z == 2 && blockIdx.x != 0) return;
  const u16* A  = z == 0 ? qbf : (z == 1 ? kbf : vbf);
  const u16* Bw = z == 0 ? Wqb : (z == 1 ? Wkb : Wvb);
  const float* bias = z == 0 ? bq : (z == 1 ? bk : bv);
  const float scale = z == 0 ? qscale : 1.0f;

  __shared__ u16 As[128 * 32];
  __shared__ u16 Bs[128 * 32];
  const int tid = threadIdx.x;
  const int lane = tid & 63;
  const int w = tid >> 6, wm = w >> 1, wn = w & 1;
  const int lo = lane & 15, hi = lane >> 4;
  const int m0 = blockIdx.y * 128, n0 = blockIdx.x * 128;
  const int r16 = lane >> 2;
  const int c8 = (lane & 3) * 8;
  const f32x4 vzero = {0.f, 0.f, 0.f, 0.f};

  f32x4 acc[4][4];
  #pragma unroll
  for (int i = 0; i < 4; ++i)
    #pragma unroll
    for (int j = 0; j < 4; ++j) acc[i][j] = vzero;

  for (int k0 = 0; k0 < K; k0 += 32) {
    #pragma unroll
    for (int it = 0; it < 2; ++it) {
      const int rg = w * 2 + it;
      const int row = rg * 16 + r16;
      gload16(&A[(long)(m0 + row) * K + k0 + c8], &As[rg * 512]);
      gload16(&Bw[(long)(n0 + row) * K + k0 + c8], &Bs[rg * 512]);
    }
    __syncthreads();
    bf16x8 af[4], bfr[4];
    #pragma unroll
    for (int mi = 0; mi < 4; ++mi)
      af[mi] = *reinterpret_cast<const bf16x8*>(&As[(wm * 64 + mi * 16 + lo) * 32 + hi * 8]);
    #pragma unroll
    for (int nj = 0; nj < 4; ++nj)
      bfr[nj] = *reinterpret_cast<const bf16x8*>(&Bs[(wn * 64 + nj * 16 + lo) * 32 + hi * 8]);
    #pragma unroll
    for (int mi = 0; mi < 4; ++mi)
      #pragma unroll
      for (int nj = 0; nj < 4; ++nj)
        acc[mi][nj] = mfma16(af[mi], bfr[nj], acc[mi][nj]);
    __syncthreads();
  }

  #pragma unroll
  for (int nj = 0; nj < 4; ++nj) {
    const int n = n0 + wn * 64 + nj * 16 + lo;
    if (z == 2 && n >= 64) continue;
    const float bb = bias[n];
    #pragma unroll
    for (int mi = 0; mi < 4; ++mi) {
      #pragma unroll
      for (int r = 0; r < 4; ++r) {
        const int mm = m0 + wm * 64 + mi * 16 + hi * 4 + r;
        const int bidx = mm >> 11, ss = mm & 2047;
        const float val = (acc[mi][nj][r] + bb) * scale;
        if (z < 2) {
          const int hh = n >> 6, ee = n & 63;
          const long idx = bidx * 2097152L + ss * 64L + hh * 131072L + ee;
          (z ? kh : qh)[idx] = f2bf(val);
        } else {
          vT[bidx * 131072L + n * 2048L + ss] = f2bf(val);
        }
      }
    }
  }
}

// ---------------- generic bf16 GEMM (final proj), global_load_lds staging
__global__ __launch_bounds__(256) void gemm_bt(
    const u16* __restrict__ A, const u16* __restrict__ Bw,
    const float* __restrict__ bias, int M, int N, int K, float scale,
    u16* __restrict__ outb, float* __restrict__ outf,
    int DHn, long strideB, long strideS, long strideH, long strideE) {
  __shared__ u16 As[128 * 32];
  __shared__ u16 Bs[128 * 32];
  const int tid = threadIdx.x;
  const int lane = tid & 63;
  const int w = tid >> 6, wm = w >> 1, wn = w & 1;
  const int lo = lane & 15, hi = lane >> 4;
  const int m0 = blockIdx.y * 128, n0 = blockIdx.x * 128;
  const int r16 = lane >> 2;
  const int c8 = (lane & 3) * 8;
  const f32x4 vzero = {0.f, 0.f, 0.f, 0.f};

  f32x4 acc[4][4];
  #pragma unroll
  for (int i = 0; i < 4; ++i)
    #pragma unroll
    for (int j = 0; j < 4; ++j) acc[i][j] = vzero;

  for (int k0 = 0; k0 < K; k0 += 32) {
    #pragma unroll
    for (int it = 0; it < 2; ++it) {
      const int rg = w * 2 + it;
      const int row = rg * 16 + r16;
      gload16(&A[(long)(m0 + row) * K + k0 + c8], &As[rg * 512]);
      gload16(&Bw[(long)(n0 + row) * K + k0 + c8], &Bs[rg * 512]);
    }
    __syncthreads();
    bf16x8 af[4], bfr[4];
    #pragma unroll
    for (int mi = 0; mi < 4; ++mi)
      af[mi] = *reinterpret_cast<const bf16x8*>(&As[(wm * 64 + mi * 16 + lo) * 32 + hi * 8]);
    #pragma unroll
    for (int nj = 0; nj < 4; ++nj)
      bfr[nj] = *reinterpret_cast<const bf16x8*>(&Bs[(wn * 64 + nj * 16 + lo) * 32 + hi * 8]);
    #pragma unroll
    for (int mi = 0; mi < 4; ++mi)
      #pragma unroll
      for (int nj = 0; nj < 4; ++nj)
        acc[mi][nj] = mfma16(af[mi], bfr[nj], acc[mi][nj]);
    __syncthreads();
  }

  #pragma unroll
  for (int nj = 0; nj < 4; ++nj) {
    const int n = n0 + wn * 64 + nj * 16 + lo;
    if (n >= N) continue;
    const float bb = bias ? bias[n] : 0.f;
    const int hh = n / DHn, ee = n % DHn;
    #pragma unroll
    for (int mi = 0; mi < 4; ++mi) {
      #pragma unroll
      for (int r = 0; r < 4; ++r) {
        const int mm = m0 + wm * 64 + mi * 16 + hi * 4 + r;
        const int bidx = mm >> 11, ss = mm & 2047;
        const long idx = bidx * strideB + ss * strideS + hh * strideH + ee * strideE;
        const float val = (acc[mi][nj][r] + bb) * scale;
        if (outf) outf[idx] = val;
        else outb[idx] = f2bf(val);
      }
    }
  }
}

// ---------------- fused causal attention (r13 + interleaved strip pair)
// Both strips of the pair {A=idx, B=127-idx} share (b,h), so kh rows and vT
// cols are loaded ONCE per iteration and consumed by both strips.
// Fixed-max softmax in exp2 domain (qh pre-scaled by log2(e)/8), M0=16.
// Pass 1 (mfma(Q,K)): l-sums for both strips, shared kh loads.
// Pass 2 (mfma(K,Q) z^T): p -> per-strip pslds -> 256B-segment nt stores + PV,
// one lgkm wait per iteration, shared kh + vT loads.
__global__ __launch_bounds__(256) void attn_fused(
    const u16* __restrict__ qh, const u16* __restrict__ kh,
    const u16* __restrict__ vT, u16* __restrict__ outh,
    float* __restrict__ attn_out) {
  __shared__ float pslds[2][4][16][68];  // [strip][wave][row][col]
  __shared__ float pofflds[2][4][16];
  const int tid = threadIdx.x;
  const int lane = tid & 63, w = tid >> 6;
  const int lo = lane & 15, hi = lane >> 4;
  const int blk = blockIdx.x;
  const int sb = blk & 15, h = (blk >> 4) & 15, b = blk >> 8;
  const long bh = (long)(b * Hc + h) * Sc;
  const long rowstride = (long)Hc * Sc;  // 32768
  float* aout = attn_out + (long)b * Sc * rowstride + (long)h * Sc;
  float (*pfA)[68] = pslds[0][w];
  float (*pfB)[68] = pslds[1][w];
  float* poffA = pofflds[0][w];
  float* poffB = pofflds[1][w];
  const f32x4 vzero = {0.f, 0.f, 0.f, 0.f};
  const int idx = sb * 4 + w;        // 0..63
  const float M0 = 16.f;

  const int s0A = idx * 16;          // short strip
  const int s0B = (127 - idx) * 16;  // long strip
  const int sendA = (s0A + 79) & ~63;
  const int sendB = (s0B + 79) & ~63;  // sendA < sendB always
  const int srowA = s0A + hi * 4;      // pass-1 row bases
  const int srowB = s0B + hi * 4;
  const int srow2A = s0A + lo;         // pass-2 rows
  const int srow2B = s0B + lo;

  bf16x8 qaA0, qaA1, qaB0, qaB1;
  {
    const u16* qpA = &qh[(bh + s0A + lo) * DHc];
    qaA0 = *reinterpret_cast<const bf16x8*>(&qpA[hi * 8]);
    qaA1 = *reinterpret_cast<const bf16x8*>(&qpA[32 + hi * 8]);
    const u16* qpB = &qh[(bh + s0B + lo) * DHc];
    qaB0 = *reinterpret_cast<const bf16x8*>(&qpB[hi * 8]);
    qaB1 = *reinterpret_cast<const bf16x8*>(&qpB[32 + hi * 8]);
  }

  // ---- pass 1: l = sum exp2(z-M0) for both strips, shared kh loads ----
  float lrA[4], lrB[4];
  #pragma unroll
  for (int r = 0; r < 4; ++r) { lrA[r] = 0.f; lrB[r] = 0.f; }

  for (int t0 = 0; t0 < sendB; t0 += 64) {
    bf16x8 kb[4][2];
    #pragma unroll
    for (int c = 0; c < 4; ++c) {
      const u16* kp = &kh[(bh + t0 + c * 16 + lo) * DHc];
      kb[c][0] = *reinterpret_cast<const bf16x8*>(&kp[hi * 8]);
      kb[c][1] = *reinterpret_cast<const bf16x8*>(&kp[32 + hi * 8]);
    }
    const bool doA = (t0 < sendA);  // wave-uniform
    {
      const bool fullB = (t0 + 63 <= s0B);
      #pragma unroll
      for (int c = 0; c < 4; ++c) {
        f32x4 z = mfma16(qaB1, kb[c][1], mfma16(qaB0, kb[c][0], vzero));
        #pragma unroll
        for (int r = 0; r < 4; ++r) {
          float e = exp2f(z[r] - M0);
          if (!fullB) e = ((t0 + c * 16 + lo) <= srowB + r) ? e : 0.f;
          lrB[r] += e;
        }
      }
    }
    if (doA) {
      const bool fullA = (t0 + 63 <= s0A);
      #pragma unroll
      for (int c = 0; c < 4; ++c) {
        f32x4 z = mfma16(qaA1, kb[c][1], mfma16(qaA0, kb[c][0], vzero));
        #pragma unroll
        for (int r = 0; r < 4; ++r) {
          float e = exp2f(z[r] - M0);
          if (!fullA) e = ((t0 + c * 16 + lo) <= srowA + r) ? e : 0.f;
          lrA[r] += e;
        }
      }
    }
  }
  // reduce across the 16 column-lanes; publish off = M0 + log2(l)
  #pragma unroll
  for (int r = 0; r < 4; ++r) {
    #pragma unroll
    for (int dd = 1; dd < 16; dd <<= 1) {
      lrA[r] += __shfl_xor(lrA[r], dd);
      lrB[r] += __shfl_xor(lrB[r], dd);
    }
  }
  if (lo == 0) {
    #pragma unroll
    for (int r = 0; r < 4; ++r) {
      poffA[hi * 4 + r] = M0 + __log2f(lrA[r]);
      poffB[hi * 4 + r] = M0 + __log2f(lrB[r]);
    }
  }
  asm volatile("s_waitcnt lgkmcnt(0)" ::: "memory");
  __builtin_amdgcn_sched_barrier(0);
  const float offA = poffA[lo];
  const float offB = poffB[lo];

  // ---- pass 2: z^T recompute both strips, shared kh+vT loads, one wait/iter ----
  f32x4 accoA[4], accoB[4];
  #pragma unroll
  for (int eb = 0; eb < 4; ++eb) { accoA[eb] = vzero; accoB[eb] = vzero; }
  const int r4 = lane >> 4;        // store row-within-quad
  const int c4 = (lane & 15) * 4;  // store col

  for (int t0 = 0; t0 < sendB; t0 += 64) {
    bf16x8 kb[4][2];
    #pragma unroll
    for (int c = 0; c < 4; ++c) {
      const u16* kp = &kh[(bh + t0 + c * 16 + lo) * DHc];
      kb[c][0] = *reinterpret_cast<const bf16x8*>(&kp[hi * 8]);
      kb[c][1] = *reinterpret_cast<const bf16x8*>(&kp[32 + hi * 8]);
    }
    const bool doA = (t0 < sendA);  // wave-uniform
    {
      const bool fullB = (t0 + 63 <= s0B);
      #pragma unroll
      for (int c = 0; c < 4; ++c) {
        f32x4 zt = mfma16(kb[c][1], qaB1, mfma16(kb[c][0], qaB0, vzero));
        f32x4 p;
        #pragma unroll
        for (int r = 0; r < 4; ++r) {
          const float e = exp2f(zt[r] - offB);
          p[r] = (fullB || (t0 + c * 16 + hi * 4 + r <= srow2B)) ? e : 0.f;
        }
        *reinterpret_cast<f32x4*>(&pfB[lo][c * 16 + hi * 4]) = p;
      }
    }
    if (doA) {
      const bool fullA = (t0 + 63 <= s0A);
      #pragma unroll
      for (int c = 0; c < 4; ++c) {
        f32x4 zt = mfma16(kb[c][1], qaA1, mfma16(kb[c][0], qaA0, vzero));
        f32x4 p;
        #pragma unroll
        for (int r = 0; r < 4; ++r) {
          const float e = exp2f(zt[r] - offA);
          p[r] = (fullA || (t0 + c * 16 + hi * 4 + r <= srow2A)) ? e : 0.f;
        }
        *reinterpret_cast<f32x4*>(&pfA[lo][c * 16 + hi * 4]) = p;
      }
    }
    asm volatile("s_waitcnt lgkmcnt(0)" ::: "memory");
    __builtin_amdgcn_sched_barrier(0);
    // transposed nontemporal stores: 4 rows x 256B contiguous per inst
    #pragma unroll
    for (int j = 0; j < 4; ++j) {
      f32x4 v = *reinterpret_cast<const f32x4*>(&pfB[j * 4 + r4][c4]);
      __builtin_nontemporal_store(
          v, reinterpret_cast<f32x4*>(aout + (long)(s0B + j * 4 + r4) * rowstride + t0 + c4));
    }
    if (doA) {
      #pragma unroll
      for (int j = 0; j < 4; ++j) {
        f32x4 v = *reinterpret_cast<const f32x4*>(&pfA[j * 4 + r4][c4]);
        __builtin_nontemporal_store(
            v, reinterpret_cast<f32x4*>(aout + (long)(s0A + j * 4 + r4) * rowstride + t0 + c4));
      }
    }
    // PV: vT fragments loaded once, consumed by both strips
    bf16x8 vb[4][2];
    const u16* vp = &vT[((long)b * DHc + lo) * Sc + t0 + hi * 8];
    #pragma unroll
    for (int eb = 0; eb < 4; ++eb) {
      vb[eb][0] = *reinterpret_cast<const bf16x8*>(&vp[(long)eb * 16 * Sc]);
      vb[eb][1] = *reinterpret_cast<const bf16x8*>(&vp[(long)eb * 16 * Sc + 32]);
    }
    {
      f32x4 a0 = *reinterpret_cast<const f32x4*>(&pfB[lo][hi * 8]);
      f32x4 a1 = *reinterpret_cast<const f32x4*>(&pfB[lo][hi * 8 + 4]);
      f32x4 a2 = *reinterpret_cast<const f32x4*>(&pfB[lo][32 + hi * 8]);
      f32x4 a3 = *reinterpret_cast<const f32x4*>(&pfB[lo][32 + hi * 8 + 4]);
      bf16x8 pa0 = pk8(a0, a1);
      bf16x8 pa1 = pk8(a2, a3);
      #pragma unroll
      for (int eb = 0; eb < 4; ++eb)
        accoB[eb] = mfma16(pa1, vb[eb][1], mfma16(pa0, vb[eb][0], accoB[eb]));
    }
    if (doA) {
      f32x4 a0 = *reinterpret_cast<const f32x4*>(&pfA[lo][hi * 8]);
      f32x4 a1 = *reinterpret_cast<const f32x4*>(&pfA[lo][hi * 8 + 4]);
      f32x4 a2 = *reinterpret_cast<const f32x4*>(&pfA[lo][32 + hi * 8]);
      f32x4 a3 = *reinterpret_cast<const f32x4*>(&pfA[lo][32 + hi * 8 + 4]);
      bf16x8 pa0 = pk8(a0, a1);
      bf16x8 pa1 = pk8(a2, a3);
      #pragma unroll
      for (int eb = 0; eb < 4; ++eb)
        accoA[eb] = mfma16(pa1, vb[eb][1], mfma16(pa0, vb[eb][0], accoA[eb]));
    }
  }

  // ---- epilogue: outh stores + nt zero-fill of both masked regions ----
  #pragma unroll
  for (int eb = 0; eb < 4; ++eb)
    #pragma unroll
    for (int r = 0; r < 4; ++r) {
      outh[(bh + srowA + r) * DHc + eb * 16 + lo] = f2bf(accoA[eb][r]);
      outh[(bh + srowB + r) * DHc + eb * 16 + lo] = f2bf(accoB[eb][r]);
    }

  const f32x4 z4 = {0.f, 0.f, 0.f, 0.f};
  for (int t0 = sendA; t0 < Sc; t0 += 64) {
    #pragma unroll
    for (int r = 0; r < 4; ++r)
      __builtin_nontemporal_store(
          z4, reinterpret_cast<f32x4*>(aout + (long)(srowA + r) * rowstride + t0 + lo * 4));
  }
  for (int t0 = sendB; t0 < Sc; t0 += 64) {
    #pragma unroll
    for (int r = 0; r < 4; ++r)
      __builtin_nontemporal_store(
          z4, reinterpret_cast<f32x4*>(aout + (long)(srowB + r) * rowstride + t0 + lo * 4));
  }
}

// ---------------- mean over heads
__global__ __launch_bounds__(256) void mean_kernel(const u16* __restrict__ outh,
                                                   u16* __restrict__ meanb) {
  const int idx = blockIdx.x * 256 + threadIdx.x;  // 32768 threads
  const int bs = idx >> 3;
  const int e0 = (idx & 7) * 8;
  const int b = bs >> 11, s = bs & 2047;
  float acc[8];
  #pragma unroll
  for (int j = 0; j < 8; ++j) acc[j] = 0.f;
  for (int h = 0; h < Hc; ++h) {
    alignas(16) u16 tmp[8];
    *reinterpret_cast<uint4*>(tmp) =
        *reinterpret_cast<const uint4*>(&outh[((long)(b * Hc + h) * Sc + s) * DHc + e0]);
    #pragma unroll
    for (int j = 0; j < 8; ++j) acc[j] += bf2f(tmp[j]);
  }
  alignas(16) u16 o[8];
  #pragma unroll
  for (int j = 0; j < 8; ++j) o[j] = f2bf(acc[j] * 0.0625f);
  *reinterpret_cast<uint4*>(&meanb[(long)bs * DHc + e0]) = *reinterpret_cast<const uint4*>(o);
}

extern "C" void kernel_launch(void* const* d_in, const int* in_sizes, int n_in,
                              void* d_out, int out_size, void* d_ws, size_t ws_size,
                              hipStream_t stream) {
  (void)in_sizes; (void)n_in; (void)out_size; (void)ws_size;
  const float* q  = (const float*)d_in[0];
  const float* k  = (const float*)d_in[1];
  const float* v  = (const float*)d_in[2];
  const float* Wv = (const float*)d_in[4];
  const float* bv = (const float*)d_in[5];
  const float* Wq = (const float*)d_in[6];
  const float* bq = (const float*)d_in[7];
  const float* Wk = (const float*)d_in[8];
  const float* bk = (const float*)d_in[9];
  const float* Wo = (const float*)d_in[10];

  char* ws = (char*)d_ws;
  u16* qbf   = (u16*)(ws + 0);          // 8.0 MB
  u16* kbf   = (u16*)(ws + 8388608);
  u16* vbf   = (u16*)(ws + 16777216);
  u16* Wqbf  = (u16*)(ws + 25165824);   // 2 MB
  u16* Wkbf  = (u16*)(ws + 27262976);
  u16* Wvbf  = (u16*)(ws + 29360128);   // 128 KB (B staging may read into Wobf: defined)
  u16* Wobf  = (u16*)(ws + 29491200);
  u16* qhb   = (u16*)(ws + 29622272);   // 8 MB  [B,H,S,DH]
  u16* khb   = (u16*)(ws + 38010880);
  u16* vTb   = (u16*)(ws + 46399488);   // 512 KB [B,DH,S]
  u16* outh  = (u16*)(ws + 46923776);   // 8 MB  [B,H,S,DH]
  u16* meanb = (u16*)(ws + 55312384);   // 512 KB

  float* outp  = (float*)d_out;
  float* attnp = (float*)d_out + (long)Bc * Sc * Dc;

  // one launch: all f32 -> bf16 conversions (3.7M float4)
  cvt_all<<<(3702784 + 255) / 256, 256, 0, stream>>>(
      q, k, v, Wq, Wk, Wv, Wo, qbf, kbf, vbf, Wqbf, Wkbf, Wvbf, Wobf);

  const int M = Bc * Sc;  // 4096
  // qh scale folds 1/sqrt(DH) AND log2(e): attention runs in exp2 domain
  const float qscale = 0.125f * 1.4426950408889634f;
  gemm_qkv<<<dim3(8, 32, 3), 256, 0, stream>>>(
      qbf, kbf, vbf, Wqbf, Wkbf, Wvbf, bq, bk, bv, qscale, qhb, khb, vTb);

  attn_fused<<<512, 256, 0, stream>>>(qhb, khb, vTb, outh, attnp);

  mean_kernel<<<128, 256, 0, stream>>>(outh, meanb);

  gemm_bt<<<dim3(8, 32), 256, 0, stream>>>(meanb, Wobf, nullptr, M, 1024, 64, 1.0f,
      nullptr, outp, 1024, 2097152L, 1024L, 0L, 1L);
}